// Round 4
// baseline (798.345 us; speedup 1.0000x reference)
//
#include <hip/hip_runtime.h>
#include <hip/hip_bf16.h>

#define D 128
#define K1 384
#define H 256
#define O 128
#define BE 64
#define LDEA 136       // node_proj x-tile leading dim (ushorts)
#define LDF (K1 + 8)   // fallback path feat leading dim
#define LDHF (H + 8)

typedef __attribute__((ext_vector_type(8))) short bf16x8;
typedef __attribute__((ext_vector_type(4))) float f32x4;
typedef __attribute__((ext_vector_type(2))) int i32x2;

// XOR-swizzled LDS index helpers (dense tiles, conflict-free ds_read_b128)
#define EA_SW(row, col) ((row) * 128 + ((col) ^ (((row) & 7) << 3)))   // ushort units, col<128
#define H_SW(row, col)  ((row) * 256 + ((col) ^ (((row) & 7) << 3)))   // ushort units, col<256
#define O_SW(row, col)  ((row) * 128 + ((col) ^ (((row) & 7) << 2)))   // f32 units,  col<128

__device__ inline ushort f2b(float f) {
    union { float f; unsigned u; } v; v.f = f;
    unsigned u = v.u;
    unsigned r = (u + 0x7fffu + ((u >> 16) & 1u)) >> 16;   // RNE
    return (ushort)r;
}
__device__ inline float b2f(ushort u) {
    union { unsigned u; float f; } v; v.u = ((unsigned)u) << 16; return v.f;
}
__device__ inline f32x4 ntload4(const float* p) { return __builtin_nontemporal_load((const f32x4*)p); }
__device__ inline i32x2 ntload2i(const int* p) { return __builtin_nontemporal_load((const i32x2*)p); }
__device__ inline void ntstore4(float* p, f32x4 v) { __builtin_nontemporal_store(v, (f32x4*)p); }
__device__ inline ushort4 cvt4(f32x4 v) {
    ushort4 u; u.x = f2b(v.x); u.y = f2b(v.y); u.z = f2b(v.z); u.w = f2b(v.w); return u;
}

// W1t[n][k] = bf16(W1[k][n])  (n<256, k<384) ; W2t[o][k] = bf16(W2[k][o])
__global__ void prep_weights(const float* __restrict__ W1, const float* __restrict__ W2,
                             ushort* __restrict__ W1t, ushort* __restrict__ W2t) {
    int tid = blockIdx.x * blockDim.x + threadIdx.x;
    if (tid < 256 * 384) {
        int n = tid / 384, k = tid % 384;
        W1t[tid] = f2b(W1[k * 256 + n]);
    } else {
        int t2 = tid - 256 * 384;
        if (t2 < 128 * 256) {
            int o = t2 / 256, k = t2 % 256;
            W2t[t2] = f2b(W2[k * 128 + o]);
        }
    }
}

// Per-node projections, permuted layout:
//  XA[n][row16*16 + wv*4 + fc] = bf16( (x[n] @ W1[0:128])[col] + b1[col] ),  col = wv*64+fc*16+row16
//  XB[n][same p]               = bf16( (x[n] @ W1[128:256])[col] )
__global__ __launch_bounds__(256, 2)
void node_proj(const float* __restrict__ x, const float* __restrict__ b1,
               const ushort* __restrict__ W1t,
               ushort* __restrict__ XA, ushort* __restrict__ XB, int N) {
    __shared__ ushort sX[64 * LDEA];
    const int tid = threadIdx.x, wave = tid >> 6, lane = tid & 63;
    const int row16 = lane & 15, kgrp = lane >> 4;
    const long n0 = (long)blockIdx.x * 64;

    {   // stage x tile (64 nodes x 128) as bf16
        int i = tid >> 2, p = tid & 3;
        long n = n0 + i; if (n >= N) n = N - 1;
        const float* src = x + n * D + p * 32;
        ushort* dst = sX + i * LDEA + p * 32;
        #pragma unroll
        for (int j = 0; j < 8; ++j) {
            float4 v = ((const float4*)src)[j];
            ushort4 u; u.x = f2b(v.x); u.y = f2b(v.y); u.z = f2b(v.z); u.w = f2b(v.w);
            *(ushort4*)(dst + j * 4) = u;
        }
    }
    __syncthreads();

    f32x4 accA[4][4], accB[4][4];
    #pragma unroll
    for (int a = 0; a < 4; ++a)
        #pragma unroll
        for (int b = 0; b < 4; ++b) { accA[a][b] = (f32x4){0,0,0,0}; accB[a][b] = (f32x4){0,0,0,0}; }

    const int wcol = wave * 64;
    #pragma unroll
    for (int ks = 0; ks < 4; ++ks) {
        int k0 = ks * 32;
        bf16x8 a[4], bA[4], bB[4];
        #pragma unroll
        for (int fr = 0; fr < 4; ++fr)
            a[fr] = *(const bf16x8*)(sX + (fr * 16 + row16) * LDEA + k0 + kgrp * 8);
        #pragma unroll
        for (int fc = 0; fc < 4; ++fc) {
            const ushort* wb = W1t + (wcol + fc * 16 + row16) * K1 + k0 + kgrp * 8;
            bA[fc] = *(const bf16x8*)(wb);
            bB[fc] = *(const bf16x8*)(wb + 128);
        }
        #pragma unroll
        for (int fr = 0; fr < 4; ++fr)
            #pragma unroll
            for (int fc = 0; fc < 4; ++fc) {
                accA[fr][fc] = __builtin_amdgcn_mfma_f32_16x16x32_bf16(a[fr], bA[fc], accA[fr][fc], 0, 0, 0);
                accB[fr][fc] = __builtin_amdgcn_mfma_f32_16x16x32_bf16(a[fr], bB[fc], accB[fr][fc], 0, 0, 0);
            }
    }

    float bv[4];
    #pragma unroll
    for (int fc = 0; fc < 4; ++fc) bv[fc] = b1[wcol + fc * 16 + row16];

    #pragma unroll
    for (int fr = 0; fr < 4; ++fr)
        #pragma unroll
        for (int r = 0; r < 4; ++r) {
            long n = n0 + fr * 16 + kgrp * 4 + r;
            if (n < N) {
                ushort4 ua, ub;
                ua.x = f2b(accA[fr][0][r] + bv[0]); ua.y = f2b(accA[fr][1][r] + bv[1]);
                ua.z = f2b(accA[fr][2][r] + bv[2]); ua.w = f2b(accA[fr][3][r] + bv[3]);
                ub.x = f2b(accB[fr][0][r]); ub.y = f2b(accB[fr][1][r]);
                ub.z = f2b(accB[fr][2][r]); ub.w = f2b(accB[fr][3][r]);
                long p = n * 256 + row16 * 16 + wave * 4;
                *(ushort4*)(XA + p) = ua;
                *(ushort4*)(XB + p) = ub;
            }
        }
}

__global__ __launch_bounds__(256, 4)
void edge_mlp3(const float* __restrict__ ea, const int* __restrict__ eidx,
               const ushort* __restrict__ XA, const ushort* __restrict__ XB,
               const ushort* __restrict__ W1t, const ushort* __restrict__ W2t,
               const float* __restrict__ b2, float* __restrict__ out, int E) {
    __shared__ __align__(16) ushort sBuf[16384];   // 32768 B; sEA -> sH -> sOut aliased
    ushort* sEA = sBuf;
    ushort* sH  = sBuf;
    float*  sOut = (float*)sBuf;

    const int tid = threadIdx.x, wave = tid >> 6, lane = tid & 63;
    const int row16 = lane & 15, kgrp = lane >> 4;
    const long e0 = (long)blockIdx.x * BE;

    // ---- 1) eidx loads first: longest dependency chain (eidx -> gather -> acc) ----
    i32x2 se[4][4];
    #pragma unroll
    for (int fr = 0; fr < 4; ++fr)
        #pragma unroll
        for (int r = 0; r < 4; ++r) {
            long e = e0 + fr * 16 + kgrp * 4 + r; if (e >= E) e = E - 1;
            se[fr][r] = ntload2i(eidx + 2 * e);
        }

    // ---- 2) gathers of per-node projections (L3-resident tables, cached loads) ----
    ushort4 ga[4][4], gb[4][4];
    const int poff = row16 * 16 + wave * 4;
    #pragma unroll
    for (int fr = 0; fr < 4; ++fr)
        #pragma unroll
        for (int r = 0; r < 4; ++r) {
            ga[fr][r] = *(const ushort4*)(XA + (long)se[fr][r][0] * 256 + poff);
            gb[fr][r] = *(const ushort4*)(XB + (long)se[fr][r][1] * 256 + poff);
        }

    // ---- 3) ea tile: nontemporal f32 loads -> bf16 -> swizzled LDS ----
    {
        const int si = tid >> 2, sp = tid & 3;
        long ee = e0 + si; if (ee >= E) ee = E - 1;
        const float* src = ea + ee * D + sp * 32;
        f32x4 ev[8];
        #pragma unroll
        for (int j = 0; j < 8; ++j) ev[j] = ntload4(src + j * 4);
        #pragma unroll
        for (int j = 0; j < 8; ++j)
            *(ushort4*)(sEA + EA_SW(si, sp * 32 + j * 4)) = cvt4(ev[j]);
    }

    // ---- 4) init acc from gathers ----
    f32x4 acc[4][4];
    #pragma unroll
    for (int fr = 0; fr < 4; ++fr)
        #pragma unroll
        for (int r = 0; r < 4; ++r) {
            const ushort* pa = (const ushort*)&ga[fr][r];
            const ushort* pb = (const ushort*)&gb[fr][r];
            #pragma unroll
            for (int fc = 0; fc < 4; ++fc)
                acc[fr][fc][r] = b2f(pa[fc]) + b2f(pb[fc]);
        }
    __syncthreads();

    // ---- phase 1: acc += ea @ W1c   (K=128, W1c = W1t rows k 256..384) ----
    const int wcol = wave * 64;
    #pragma unroll
    for (int ks = 0; ks < 4; ++ks) {
        int k0 = ks * 32;
        bf16x8 a[4], b[4];
        #pragma unroll
        for (int fr = 0; fr < 4; ++fr)
            a[fr] = *(const bf16x8*)(sEA + EA_SW(fr * 16 + row16, k0 + kgrp * 8));
        #pragma unroll
        for (int fc = 0; fc < 4; ++fc)
            b[fc] = *(const bf16x8*)(W1t + (wcol + fc * 16 + row16) * K1 + 256 + k0 + kgrp * 8);
        #pragma unroll
        for (int fr = 0; fr < 4; ++fr)
            #pragma unroll
            for (int fc = 0; fc < 4; ++fc)
                acc[fr][fc] = __builtin_amdgcn_mfma_f32_16x16x32_bf16(a[fr], b[fc], acc[fr][fc], 0, 0, 0);
    }
    __syncthreads();   // all sEA reads done before aliasing as sH

    // ---- relu + h -> LDS (bf16, swizzled) ----
    #pragma unroll
    for (int fr = 0; fr < 4; ++fr)
        #pragma unroll
        for (int r = 0; r < 4; ++r) {
            int row = fr * 16 + kgrp * 4 + r;
            #pragma unroll
            for (int fc = 0; fc < 4; ++fc) {
                float v = fmaxf(acc[fr][fc][r], 0.f);
                sH[H_SW(row, wcol + fc * 16 + row16)] = f2b(v);
            }
        }
    __syncthreads();

    // ---- phase 2: out = h @ W2 + b2 ----
    f32x4 acc2[4][2];
    #pragma unroll
    for (int a = 0; a < 4; ++a)
        #pragma unroll
        for (int b = 0; b < 2; ++b) acc2[a][b] = (f32x4){0,0,0,0};

    const int wo = wave * 32;
    #pragma unroll
    for (int ks = 0; ks < 8; ++ks) {
        int k0 = ks * 32;
        bf16x8 a[4], b[2];
        #pragma unroll
        for (int fr = 0; fr < 4; ++fr)
            a[fr] = *(const bf16x8*)(sH + H_SW(fr * 16 + row16, k0 + kgrp * 8));
        #pragma unroll
        for (int fc = 0; fc < 2; ++fc)
            b[fc] = *(const bf16x8*)(W2t + (wo + fc * 16 + row16) * H + k0 + kgrp * 8);
        #pragma unroll
        for (int fr = 0; fr < 4; ++fr)
            #pragma unroll
            for (int fc = 0; fc < 2; ++fc)
                acc2[fr][fc] = __builtin_amdgcn_mfma_f32_16x16x32_bf16(a[fr], b[fc], acc2[fr][fc], 0, 0, 0);
    }
    __syncthreads();   // all sH reads done before aliasing as sOut

    // ---- stage out tile (f32, swizzled) ----
    {
        float bv[2];
        #pragma unroll
        for (int fc = 0; fc < 2; ++fc) bv[fc] = b2[wo + fc * 16 + row16];
        #pragma unroll
        for (int fc = 0; fc < 2; ++fc)
            #pragma unroll
            for (int fr = 0; fr < 4; ++fr)
                #pragma unroll
                for (int r = 0; r < 4; ++r) {
                    int row = fr * 16 + kgrp * 4 + r;
                    sOut[O_SW(row, wo + fc * 16 + row16)] = acc2[fr][fc][r] + bv[fc];
                }
    }
    __syncthreads();

    // ---- coalesced nontemporal out store: thread -> 32 contiguous floats of one row ----
    {
        const int orow = tid >> 2, op = tid & 3;
        long eo = e0 + orow;
        if (eo < E) {
            float* dst = out + eo * O + op * 32;
            #pragma unroll
            for (int j = 0; j < 8; ++j) {
                f32x4 v = *(const f32x4*)(sOut + O_SW(orow, op * 32 + j * 4));
                ntstore4(dst + j * 4, v);
            }
        }
    }
}

// ---------------- fallback (round-1) kernel: used only if ws too small ----------------
__global__ __launch_bounds__(256, 2)
void edge_mlp(const float* __restrict__ x, const float* __restrict__ ea,
              const int* __restrict__ eidx,
              const float* __restrict__ b1, const float* __restrict__ b2,
              const ushort* __restrict__ W1t, const ushort* __restrict__ W2t,
              float* __restrict__ out, int E) {
    __shared__ ushort sF[BE * LDF];
    ushort* sH = sF;
    const int tid = threadIdx.x, wave = tid >> 6, lane = tid & 63;
    const int row16 = lane & 15, kgrp = lane >> 4;
    const long e0 = (long)blockIdx.x * BE;
    {
        int i = tid >> 2, p = tid & 3;
        long e = e0 + i; if (e >= E) e = E - 1;
        int s = eidx[2 * e], r = eidx[2 * e + 1];
        const float* src0 = x + (long)s * D + p * 32;
        const float* src1 = x + (long)r * D + p * 32;
        const float* src2 = ea + e * D + p * 32;
        ushort* dst = sF + i * LDF + p * 32;
        #pragma unroll
        for (int j = 0; j < 8; ++j) {
            float4 v = ((const float4*)src0)[j];
            ushort4 u; u.x = f2b(v.x); u.y = f2b(v.y); u.z = f2b(v.z); u.w = f2b(v.w);
            *(ushort4*)(dst + 0 * D + j * 4) = u;
        }
        #pragma unroll
        for (int j = 0; j < 8; ++j) {
            float4 v = ((const float4*)src1)[j];
            ushort4 u; u.x = f2b(v.x); u.y = f2b(v.y); u.z = f2b(v.z); u.w = f2b(v.w);
            *(ushort4*)(dst + 1 * D + j * 4) = u;
        }
        #pragma unroll
        for (int j = 0; j < 8; ++j) {
            float4 v = ((const float4*)src2)[j];
            ushort4 u; u.x = f2b(v.x); u.y = f2b(v.y); u.z = f2b(v.z); u.w = f2b(v.w);
            *(ushort4*)(dst + 2 * D + j * 4) = u;
        }
    }
    __syncthreads();
    f32x4 acc[4][4];
    #pragma unroll
    for (int a = 0; a < 4; ++a)
        #pragma unroll
        for (int b = 0; b < 4; ++b) acc[a][b] = (f32x4){0,0,0,0};
    const int wcol = wave * 64;
    for (int k0 = 0; k0 < K1; k0 += 32) {
        bf16x8 a[4], b[4];
        #pragma unroll
        for (int fr = 0; fr < 4; ++fr)
            a[fr] = *(const bf16x8*)(sF + (fr * 16 + row16) * LDF + k0 + kgrp * 8);
        #pragma unroll
        for (int fc = 0; fc < 4; ++fc)
            b[fc] = *(const bf16x8*)(W1t + (wcol + fc * 16 + row16) * K1 + k0 + kgrp * 8);
        #pragma unroll
        for (int fr = 0; fr < 4; ++fr)
            #pragma unroll
            for (int fc = 0; fc < 4; ++fc)
                acc[fr][fc] = __builtin_amdgcn_mfma_f32_16x16x32_bf16(a[fr], b[fc], acc[fr][fc], 0, 0, 0);
    }
    __syncthreads();
    #pragma unroll
    for (int fc = 0; fc < 4; ++fc) {
        int col = wcol + fc * 16 + row16;
        float bv = b1[col];
        #pragma unroll
        for (int fr = 0; fr < 4; ++fr)
            #pragma unroll
            for (int r = 0; r < 4; ++r) {
                int row = fr * 16 + kgrp * 4 + r;
                float v = fmaxf(acc[fr][fc][r] + bv, 0.f);
                sH[row * LDHF + col] = f2b(v);
            }
    }
    __syncthreads();
    f32x4 acc2[4][2];
    #pragma unroll
    for (int a = 0; a < 4; ++a)
        #pragma unroll
        for (int b = 0; b < 2; ++b) acc2[a][b] = (f32x4){0,0,0,0};
    const int wo = wave * 32;
    for (int k0 = 0; k0 < H; k0 += 32) {
        bf16x8 a[4], b[2];
        #pragma unroll
        for (int fr = 0; fr < 4; ++fr)
            a[fr] = *(const bf16x8*)(sH + (fr * 16 + row16) * LDHF + k0 + kgrp * 8);
        #pragma unroll
        for (int fc = 0; fc < 2; ++fc)
            b[fc] = *(const bf16x8*)(W2t + (wo + fc * 16 + row16) * H + k0 + kgrp * 8);
        #pragma unroll
        for (int fr = 0; fr < 4; ++fr)
            #pragma unroll
            for (int fc = 0; fc < 2; ++fc)
                acc2[fr][fc] = __builtin_amdgcn_mfma_f32_16x16x32_bf16(a[fr], b[fc], acc2[fr][fc], 0, 0, 0);
    }
    #pragma unroll
    for (int fc = 0; fc < 2; ++fc) {
        int col = wo + fc * 16 + row16;
        float bv = b2[col];
        #pragma unroll
        for (int fr = 0; fr < 4; ++fr)
            #pragma unroll
            for (int r = 0; r < 4; ++r) {
                long row = e0 + fr * 16 + kgrp * 4 + r;
                if (row < E) out[row * O + col] = acc2[fr][fc][r] + bv;
            }
    }
}

extern "C" void kernel_launch(void* const* d_in, const int* in_sizes, int n_in,
                              void* d_out, int out_size, void* d_ws, size_t ws_size,
                              hipStream_t stream) {
    const float* x  = (const float*)d_in[0];
    const float* ea = (const float*)d_in[1];
    const float* W1 = (const float*)d_in[2];
    const float* b1 = (const float*)d_in[3];
    const float* W2 = (const float*)d_in[4];
    const float* b2 = (const float*)d_in[5];
    const int* eidx = (const int*)d_in[6];
    float* out = (float*)d_out;

    const int E = in_sizes[1] / D;          // 500000
    const int N = in_sizes[0] / D;          // 50000

    ushort* W1t = (ushort*)d_ws;                    // 256*384
    ushort* W2t = W1t + 256 * 384;                  // 128*256
    ushort* XA  = W2t + 128 * 256;                  // N*256
    ushort* XB  = XA + (size_t)N * 256;             // N*256
    size_t need = (size_t)(256 * 384 + 128 * 256) * 2 + (size_t)N * 256 * 2 * 2;

    prep_weights<<<512, 256, 0, stream>>>(W1, W2, W1t, W2t);

    int nb = (E + BE - 1) / BE;
    if (ws_size >= need) {
        int nbn = (N + 63) / 64;
        node_proj<<<nbn, 256, 0, stream>>>(x, b1, W1t, XA, XB, N);
        edge_mlp3<<<nb, 256, 0, stream>>>(ea, eidx, XA, XB, W1t, W2t, b2, out, E);
    } else {
        edge_mlp<<<nb, 256, 0, stream>>>(x, ea, eidx, b1, b2, W1t, W2t, out, E);
    }
}

// Round 5
// 576.421 us; speedup vs baseline: 1.3850x; 1.3850x over previous
//
#include <hip/hip_runtime.h>
#include <hip/hip_bf16.h>

#define D 128
#define K1 384
#define H 256
#define O 128
#define BE 32
#define LDEA 136       // node_proj x-tile leading dim (ushorts)
#define LDF (K1 + 8)   // fallback path feat leading dim
#define LDHF (H + 8)

typedef __attribute__((ext_vector_type(8))) short bf16x8;
typedef __attribute__((ext_vector_type(4))) float f32x4;

// XOR-swizzled LDS index helpers (dense tiles; groups of >=4 elems stay contiguous)
#define EA_SW(row, col) ((row) * 128 + ((col) ^ (((row) & 7) << 3)))   // ushort units, col<128
#define H_SW(row, col)  ((row) * 256 + ((col) ^ (((row) & 7) << 3)))   // ushort units, col<256
#define O_SW(row, col)  ((row) * 128 + ((col) ^ (((row) & 7) << 2)))   // f32 units,  col<128

__device__ inline ushort f2b(float f) {
    union { float f; unsigned u; } v; v.f = f;
    unsigned u = v.u;
    unsigned r = (u + 0x7fffu + ((u >> 16) & 1u)) >> 16;   // RNE
    return (ushort)r;
}
__device__ inline float b2f(ushort u) {
    union { unsigned u; float f; } v; v.u = ((unsigned)u) << 16; return v.f;
}
__device__ inline ushort4 cvt4(float4 v) {
    ushort4 u; u.x = f2b(v.x); u.y = f2b(v.y); u.z = f2b(v.z); u.w = f2b(v.w); return u;
}

// W1t[n][k] = bf16(W1[k][n])  (n<256, k<384) ; W2t[o][k] = bf16(W2[k][o])
__global__ void prep_weights(const float* __restrict__ W1, const float* __restrict__ W2,
                             ushort* __restrict__ W1t, ushort* __restrict__ W2t) {
    int tid = blockIdx.x * blockDim.x + threadIdx.x;
    if (tid < 256 * 384) {
        int n = tid / 384, k = tid % 384;
        W1t[tid] = f2b(W1[k * 256 + n]);
    } else {
        int t2 = tid - 256 * 384;
        if (t2 < 128 * 256) {
            int o = t2 / 256, k = t2 % 256;
            W2t[t2] = f2b(W2[k * 128 + o]);
        }
    }
}

// Per-node projections, permuted layout:
//  XA[n][row16*16 + wv*4 + fc] = bf16( (x[n] @ W1[0:128])[col] + b1[col] ),  col = wv*64+fc*16+row16
//  XB[n][same p]               = bf16( (x[n] @ W1[128:256])[col] )
__global__ __launch_bounds__(256, 2)
void node_proj(const float* __restrict__ x, const float* __restrict__ b1,
               const ushort* __restrict__ W1t,
               ushort* __restrict__ XA, ushort* __restrict__ XB, int N) {
    __shared__ ushort sX[64 * LDEA];
    const int tid = threadIdx.x, wave = tid >> 6, lane = tid & 63;
    const int row16 = lane & 15, kgrp = lane >> 4;
    const long n0 = (long)blockIdx.x * 64;

    {   // stage x tile (64 nodes x 128) as bf16
        int i = tid >> 2, p = tid & 3;
        long n = n0 + i; if (n >= N) n = N - 1;
        const float* src = x + n * D + p * 32;
        ushort* dst = sX + i * LDEA + p * 32;
        #pragma unroll
        for (int j = 0; j < 8; ++j) {
            float4 v = ((const float4*)src)[j];
            *(ushort4*)(dst + j * 4) = cvt4(v);
        }
    }
    __syncthreads();

    f32x4 accA[4][4], accB[4][4];
    #pragma unroll
    for (int a = 0; a < 4; ++a)
        #pragma unroll
        for (int b = 0; b < 4; ++b) { accA[a][b] = (f32x4){0,0,0,0}; accB[a][b] = (f32x4){0,0,0,0}; }

    const int wcol = wave * 64;
    #pragma unroll
    for (int ks = 0; ks < 4; ++ks) {
        int k0 = ks * 32;
        bf16x8 a[4], bA[4], bB[4];
        #pragma unroll
        for (int fr = 0; fr < 4; ++fr)
            a[fr] = *(const bf16x8*)(sX + (fr * 16 + row16) * LDEA + k0 + kgrp * 8);
        #pragma unroll
        for (int fc = 0; fc < 4; ++fc) {
            const ushort* wb = W1t + (wcol + fc * 16 + row16) * K1 + k0 + kgrp * 8;
            bA[fc] = *(const bf16x8*)(wb);
            bB[fc] = *(const bf16x8*)(wb + 128);
        }
        #pragma unroll
        for (int fr = 0; fr < 4; ++fr)
            #pragma unroll
            for (int fc = 0; fc < 4; ++fc) {
                accA[fr][fc] = __builtin_amdgcn_mfma_f32_16x16x32_bf16(a[fr], bA[fc], accA[fr][fc], 0, 0, 0);
                accB[fr][fc] = __builtin_amdgcn_mfma_f32_16x16x32_bf16(a[fr], bB[fc], accB[fr][fc], 0, 0, 0);
            }
    }

    float bv[4];
    #pragma unroll
    for (int fc = 0; fc < 4; ++fc) bv[fc] = b1[wcol + fc * 16 + row16];

    #pragma unroll
    for (int fr = 0; fr < 4; ++fr)
        #pragma unroll
        for (int r = 0; r < 4; ++r) {
            long n = n0 + fr * 16 + kgrp * 4 + r;
            if (n < N) {
                ushort4 ua, ub;
                ua.x = f2b(accA[fr][0][r] + bv[0]); ua.y = f2b(accA[fr][1][r] + bv[1]);
                ua.z = f2b(accA[fr][2][r] + bv[2]); ua.w = f2b(accA[fr][3][r] + bv[3]);
                ub.x = f2b(accB[fr][0][r]); ub.y = f2b(accB[fr][1][r]);
                ub.z = f2b(accB[fr][2][r]); ub.w = f2b(accB[fr][3][r]);
                long p = n * 256 + row16 * 16 + wave * 4;
                *(ushort4*)(XA + p) = ua;
                *(ushort4*)(XB + p) = ub;
            }
        }
}

// BE=32 tile, 16 KB LDS, 8 blocks/CU. Plain cached loads/stores (no nt).
__global__ __launch_bounds__(256, 8)
void edge_mlp4(const float* __restrict__ ea, const int* __restrict__ eidx,
               const ushort* __restrict__ XA, const ushort* __restrict__ XB,
               const ushort* __restrict__ W1t, const ushort* __restrict__ W2t,
               const float* __restrict__ b2, float* __restrict__ out, int E) {
    __shared__ __align__(16) ushort sBuf[8192];   // 16384 B; sEA -> sH -> sOut aliased
    ushort* sEA = sBuf;
    ushort* sH  = sBuf;
    float*  sOut = (float*)sBuf;

    const int tid = threadIdx.x, wave = tid >> 6, lane = tid & 63;
    const int row16 = lane & 15, kgrp = lane >> 4;
    const long e0 = (long)blockIdx.x * BE;

    // ---- 1) eidx first (longest chain: eidx -> gather -> acc) ----
    int2 se[2][4];
    #pragma unroll
    for (int fr = 0; fr < 2; ++fr)
        #pragma unroll
        for (int r = 0; r < 4; ++r) {
            long e = e0 + fr * 16 + kgrp * 4 + r; if (e >= E) e = E - 1;
            se[fr][r] = *(const int2*)(eidx + 2 * e);
        }

    // ---- 2) node-projection gathers (cached; tables are L2/L3 candidates) ----
    ushort4 ga[2][4], gb[2][4];
    const int poff = row16 * 16 + wave * 4;
    #pragma unroll
    for (int fr = 0; fr < 2; ++fr)
        #pragma unroll
        for (int r = 0; r < 4; ++r) {
            ga[fr][r] = *(const ushort4*)(XA + (long)se[fr][r].x * 256 + poff);
            gb[fr][r] = *(const ushort4*)(XB + (long)se[fr][r].y * 256 + poff);
        }

    // ---- 3) ea tile (32 x 128) -> bf16 swizzled LDS ----
    {
        const int si = tid >> 3, sp = tid & 7;     // row, 16-col chunk
        long ee = e0 + si; if (ee >= E) ee = E - 1;
        const float* src = ea + ee * D + sp * 16;
        float4 ev[4];
        #pragma unroll
        for (int j = 0; j < 4; ++j) ev[j] = ((const float4*)src)[j];
        #pragma unroll
        for (int j = 0; j < 4; ++j)
            *(ushort4*)(sEA + EA_SW(si, sp * 16 + j * 4)) = cvt4(ev[j]);
    }

    // ---- 4) init acc from gathers ----
    f32x4 acc[2][4];
    #pragma unroll
    for (int fr = 0; fr < 2; ++fr)
        #pragma unroll
        for (int r = 0; r < 4; ++r) {
            const ushort* pa = (const ushort*)&ga[fr][r];
            const ushort* pb = (const ushort*)&gb[fr][r];
            #pragma unroll
            for (int fc = 0; fc < 4; ++fc)
                acc[fr][fc][r] = b2f(pa[fc]) + b2f(pb[fc]);
        }
    __syncthreads();

    // ---- phase 1: acc += ea @ W1c (K=128; W1c = W1t k-cols 256..384) ----
    const int wcol = wave * 64;
    #pragma unroll
    for (int ks = 0; ks < 4; ++ks) {
        int k0 = ks * 32;
        bf16x8 a[2], b[4];
        #pragma unroll
        for (int fr = 0; fr < 2; ++fr)
            a[fr] = *(const bf16x8*)(sEA + EA_SW(fr * 16 + row16, k0 + kgrp * 8));
        #pragma unroll
        for (int fc = 0; fc < 4; ++fc)
            b[fc] = *(const bf16x8*)(W1t + (wcol + fc * 16 + row16) * K1 + 256 + k0 + kgrp * 8);
        #pragma unroll
        for (int fr = 0; fr < 2; ++fr)
            #pragma unroll
            for (int fc = 0; fc < 4; ++fc)
                acc[fr][fc] = __builtin_amdgcn_mfma_f32_16x16x32_bf16(a[fr], b[fc], acc[fr][fc], 0, 0, 0);
    }
    __syncthreads();   // sEA reads done before aliasing as sH

    // ---- relu + h -> LDS (bf16, swizzled) ----
    #pragma unroll
    for (int fr = 0; fr < 2; ++fr)
        #pragma unroll
        for (int r = 0; r < 4; ++r) {
            int row = fr * 16 + kgrp * 4 + r;
            #pragma unroll
            for (int fc = 0; fc < 4; ++fc) {
                float v = fmaxf(acc[fr][fc][r], 0.f);
                sH[H_SW(row, wcol + fc * 16 + row16)] = f2b(v);
            }
        }
    __syncthreads();

    // ---- phase 2: out = h @ W2 + b2 ----
    f32x4 acc2[2][2];
    #pragma unroll
    for (int a = 0; a < 2; ++a)
        #pragma unroll
        for (int b = 0; b < 2; ++b) acc2[a][b] = (f32x4){0,0,0,0};

    const int wo = wave * 32;
    #pragma unroll
    for (int ks = 0; ks < 8; ++ks) {
        int k0 = ks * 32;
        bf16x8 a[2], b[2];
        #pragma unroll
        for (int fr = 0; fr < 2; ++fr)
            a[fr] = *(const bf16x8*)(sH + H_SW(fr * 16 + row16, k0 + kgrp * 8));
        #pragma unroll
        for (int fc = 0; fc < 2; ++fc)
            b[fc] = *(const bf16x8*)(W2t + (wo + fc * 16 + row16) * H + k0 + kgrp * 8);
        #pragma unroll
        for (int fr = 0; fr < 2; ++fr)
            #pragma unroll
            for (int fc = 0; fc < 2; ++fc)
                acc2[fr][fc] = __builtin_amdgcn_mfma_f32_16x16x32_bf16(a[fr], b[fc], acc2[fr][fc], 0, 0, 0);
    }
    __syncthreads();   // sH reads done before aliasing as sOut

    // ---- stage out tile (f32, swizzled) ----
    {
        float bv[2];
        #pragma unroll
        for (int fc = 0; fc < 2; ++fc) bv[fc] = b2[wo + fc * 16 + row16];
        #pragma unroll
        for (int fc = 0; fc < 2; ++fc)
            #pragma unroll
            for (int fr = 0; fr < 2; ++fr)
                #pragma unroll
                for (int r = 0; r < 4; ++r) {
                    int row = fr * 16 + kgrp * 4 + r;
                    sOut[O_SW(row, wo + fc * 16 + row16)] = acc2[fr][fc][r] + bv[fc];
                }
    }
    __syncthreads();

    // ---- truly coalesced store: instruction c -> 256 consecutive float4s ----
    // lane-consecutive idx => each wave-instruction covers 1 KB contiguous
    #pragma unroll
    for (int c = 0; c < 4; ++c) {
        int idx = c * 256 + tid;           // 0..1023 float4 of the 32x128 tile
        int row = idx >> 5;                // 32 float4 per row
        int col4 = idx & 31;
        long eo = e0 + row;
        if (eo < E) {
            f32x4 v = *(const f32x4*)(sOut + O_SW(row, col4 * 4));
            *(f32x4*)(out + eo * O + col4 * 4) = v;
        }
    }
}

// ---------------- fallback kernel: used only if ws too small ----------------
__global__ __launch_bounds__(256, 2)
void edge_mlp(const float* __restrict__ x, const float* __restrict__ ea,
              const int* __restrict__ eidx,
              const float* __restrict__ b1, const float* __restrict__ b2,
              const ushort* __restrict__ W1t, const ushort* __restrict__ W2t,
              float* __restrict__ out, int E) {
    __shared__ ushort sF[64 * LDF];
    ushort* sH = sF;
    const int tid = threadIdx.x, wave = tid >> 6, lane = tid & 63;
    const int row16 = lane & 15, kgrp = lane >> 4;
    const long e0 = (long)blockIdx.x * 64;
    {
        int i = tid >> 2, p = tid & 3;
        long e = e0 + i; if (e >= E) e = E - 1;
        int s = eidx[2 * e], r = eidx[2 * e + 1];
        const float* src0 = x + (long)s * D + p * 32;
        const float* src1 = x + (long)r * D + p * 32;
        const float* src2 = ea + e * D + p * 32;
        ushort* dst = sF + i * LDF + p * 32;
        #pragma unroll
        for (int j = 0; j < 8; ++j) *(ushort4*)(dst + 0 * D + j * 4) = cvt4(((const float4*)src0)[j]);
        #pragma unroll
        for (int j = 0; j < 8; ++j) *(ushort4*)(dst + 1 * D + j * 4) = cvt4(((const float4*)src1)[j]);
        #pragma unroll
        for (int j = 0; j < 8; ++j) *(ushort4*)(dst + 2 * D + j * 4) = cvt4(((const float4*)src2)[j]);
    }
    __syncthreads();
    f32x4 acc[4][4];
    #pragma unroll
    for (int a = 0; a < 4; ++a)
        #pragma unroll
        for (int b = 0; b < 4; ++b) acc[a][b] = (f32x4){0,0,0,0};
    const int wcol = wave * 64;
    for (int k0 = 0; k0 < K1; k0 += 32) {
        bf16x8 a[4], b[4];
        #pragma unroll
        for (int fr = 0; fr < 4; ++fr)
            a[fr] = *(const bf16x8*)(sF + (fr * 16 + row16) * LDF + k0 + kgrp * 8);
        #pragma unroll
        for (int fc = 0; fc < 4; ++fc)
            b[fc] = *(const bf16x8*)(W1t + (wcol + fc * 16 + row16) * K1 + k0 + kgrp * 8);
        #pragma unroll
        for (int fr = 0; fr < 4; ++fr)
            #pragma unroll
            for (int fc = 0; fc < 4; ++fc)
                acc[fr][fc] = __builtin_amdgcn_mfma_f32_16x16x32_bf16(a[fr], b[fc], acc[fr][fc], 0, 0, 0);
    }
    __syncthreads();
    #pragma unroll
    for (int fc = 0; fc < 4; ++fc) {
        int col = wcol + fc * 16 + row16;
        float bv = b1[col];
        #pragma unroll
        for (int fr = 0; fr < 4; ++fr)
            #pragma unroll
            for (int r = 0; r < 4; ++r) {
                int row = fr * 16 + kgrp * 4 + r;
                sH[row * LDHF + col] = f2b(fmaxf(acc[fr][fc][r] + bv, 0.f));
            }
    }
    __syncthreads();
    f32x4 acc2[4][2];
    #pragma unroll
    for (int a = 0; a < 4; ++a)
        #pragma unroll
        for (int b = 0; b < 2; ++b) acc2[a][b] = (f32x4){0,0,0,0};
    const int wo = wave * 32;
    for (int k0 = 0; k0 < H; k0 += 32) {
        bf16x8 a[4], b[2];
        #pragma unroll
        for (int fr = 0; fr < 4; ++fr)
            a[fr] = *(const bf16x8*)(sH + (fr * 16 + row16) * LDHF + k0 + kgrp * 8);
        #pragma unroll
        for (int fc = 0; fc < 2; ++fc)
            b[fc] = *(const bf16x8*)(W2t + (wo + fc * 16 + row16) * H + k0 + kgrp * 8);
        #pragma unroll
        for (int fr = 0; fr < 4; ++fr)
            #pragma unroll
            for (int fc = 0; fc < 2; ++fc)
                acc2[fr][fc] = __builtin_amdgcn_mfma_f32_16x16x32_bf16(a[fr], b[fc], acc2[fr][fc], 0, 0, 0);
    }
    #pragma unroll
    for (int fc = 0; fc < 2; ++fc) {
        int col = wo + fc * 16 + row16;
        float bv = b2[col];
        #pragma unroll
        for (int fr = 0; fr < 4; ++fr)
            #pragma unroll
            for (int r = 0; r < 4; ++r) {
                long row = e0 + fr * 16 + kgrp * 4 + r;
                if (row < E) out[row * O + col] = acc2[fr][fc][r] + bv;
            }
    }
}

extern "C" void kernel_launch(void* const* d_in, const int* in_sizes, int n_in,
                              void* d_out, int out_size, void* d_ws, size_t ws_size,
                              hipStream_t stream) {
    const float* x  = (const float*)d_in[0];
    const float* ea = (const float*)d_in[1];
    const float* W1 = (const float*)d_in[2];
    const float* b1 = (const float*)d_in[3];
    const float* W2 = (const float*)d_in[4];
    const float* b2 = (const float*)d_in[5];
    const int* eidx = (const int*)d_in[6];
    float* out = (float*)d_out;

    const int E = in_sizes[1] / D;          // 500000
    const int N = in_sizes[0] / D;          // 50000

    ushort* W1t = (ushort*)d_ws;                    // 256*384
    ushort* W2t = W1t + 256 * 384;                  // 128*256
    ushort* XA  = W2t + 128 * 256;                  // N*256
    ushort* XB  = XA + (size_t)N * 256;             // N*256
    size_t need = (size_t)(256 * 384 + 128 * 256) * 2 + (size_t)N * 256 * 2 * 2;

    prep_weights<<<512, 256, 0, stream>>>(W1, W2, W1t, W2t);

    if (ws_size >= need) {
        int nbn = (N + 63) / 64;
        node_proj<<<nbn, 256, 0, stream>>>(x, b1, W1t, XA, XB, N);
        int nb = (E + BE - 1) / BE;
        edge_mlp4<<<nb, 256, 0, stream>>>(ea, eidx, XA, XB, W1t, W2t, b2, out, E);
    } else {
        int nb = (E + 63) / 64;
        edge_mlp<<<nb, 256, 0, stream>>>(x, ea, eidx, b1, b2, W1t, W2t, out, E);
    }
}

// Round 7
// 389.564 us; speedup vs baseline: 2.0493x; 1.4797x over previous
//
#include <hip/hip_runtime.h>
#include <hip/hip_bf16.h>

#define D 128
#define K1 384
#define H 256
#define O 128
#define BE 64
#define LDF (K1 + 8)   // fallback path feat leading dim
#define LDHF (H + 8)

typedef __attribute__((ext_vector_type(8))) short bf16x8;
typedef __attribute__((ext_vector_type(4))) float f32x4;

// XOR-swizzled LDS helpers (dense; 8-elem/4-elem groups stay contiguous)
#define EA_SW(row, col) ((row) * 128 + ((col) ^ (((row) & 7) << 3)))   // ushort, col<128
#define H_SW(row, col)  ((row) * 256 + ((col) ^ (((row) & 7) << 3)))   // ushort, col<256
#define O_SW(row, col)  ((row) * 128 + ((col) ^ (((row) & 7) << 2)))   // f32,   col<128

__device__ inline ushort f2b(float f) {
    union { float f; unsigned u; } v; v.f = f;
    unsigned u = v.u;
    unsigned r = (u + 0x7fffu + ((u >> 16) & 1u)) >> 16;   // RNE
    return (ushort)r;
}
__device__ inline ushort4 cvt4(float4 v) {
    ushort4 u; u.x = f2b(v.x); u.y = f2b(v.y); u.z = f2b(v.z); u.w = f2b(v.w); return u;
}

// W1t[n][k] = bf16(W1[k][n]) (n<256,k<384) ; W2t[o][k] = bf16(W2[k][o]) (o<128,k<256)
__global__ void prep_weights(const float* __restrict__ W1, const float* __restrict__ W2,
                             ushort* __restrict__ W1t, ushort* __restrict__ W2t) {
    int tid = blockIdx.x * blockDim.x + threadIdx.x;
    if (tid < 256 * 384) {
        int n = tid / 384, k = tid % 384;
        W1t[tid] = f2b(W1[k * 256 + n]);
    } else {
        int t2 = tid - 256 * 384;
        if (t2 < 128 * 256) {
            int o = t2 / 256, k = t2 % 256;
            W2t[t2] = f2b(W2[k * 128 + o]);
        }
    }
}

// Xb[n][d] = bf16(x[n][d]) — 12.8 MB table, L3-resident gather target
__global__ __launch_bounds__(256)
void prep_x(const float* __restrict__ x, ushort* __restrict__ Xb, long total8) {
    long t = (long)blockIdx.x * blockDim.x + threadIdx.x;
    if (t < total8) {
        const float* src = x + t * 8;
        float4 v0 = ((const float4*)src)[0], v1 = ((const float4*)src)[1];
        union { bf16x8 v; ushort4 u[2]; } w;
        w.u[0] = cvt4(v0); w.u[1] = cvt4(v1);
        *(bf16x8*)(Xb + t * 8) = w.v;
    }
}

// BE=64 tile, 32 KB LDS, 4 blocks/CU. Phase 1 = 3 × K=128 sub-GEMMs (xs, xr, ea),
// double-buffered 16 KB sub-tiles with loads issued before current MFMA.
__global__ __launch_bounds__(256, 4)
void edge_mlp5(const float* __restrict__ ea, const int* __restrict__ eidx,
               const ushort* __restrict__ Xb,
               const ushort* __restrict__ W1t, const ushort* __restrict__ W2t,
               const float* __restrict__ b1, const float* __restrict__ b2,
               float* __restrict__ out, int E) {
    __shared__ __align__(16) ushort sBuf[16384];   // 32 KB; s0|s1 -> sH -> sOut aliased
    ushort* s0 = sBuf;
    ushort* s1 = sBuf + 8192;
    ushort* sH = sBuf;
    float*  sOut = (float*)sBuf;

    const int tid = threadIdx.x, wave = tid >> 6, lane = tid & 63;
    const int row16 = lane & 15, kgrp = lane >> 4;
    const long e0 = (long)blockIdx.x * BE;

    // staging geometry: thread -> (row, quarter); 4 threads cover one 64-row
    const int srow = tid >> 2, sq = tid & 3;
    long se = e0 + srow; if (se >= E) se = E - 1;
    const int2 sr = *(const int2*)(eidx + 2 * se);

    // ---- stage xs -> s0 ----
    {
        const ushort* src = Xb + (long)sr.x * D + sq * 32;
        #pragma unroll
        for (int j = 0; j < 4; ++j)
            *(bf16x8*)(s0 + EA_SW(srow, sq * 32 + j * 8)) = *(const bf16x8*)(src + j * 8);
    }

    f32x4 acc[4][4];
    #pragma unroll
    for (int a = 0; a < 4; ++a)
        #pragma unroll
        for (int b = 0; b < 4; ++b) acc[a][b] = (f32x4){0, 0, 0, 0};

    const int wcol = wave * 64;

#define PHASE1_MFMA(SRC, KBASE)                                                              \
    {                                                                                        \
        _Pragma("unroll")                                                                    \
        for (int ks = 0; ks < 4; ++ks) {                                                     \
            int k0 = ks * 32;                                                                \
            bf16x8 a[4], b[4];                                                               \
            _Pragma("unroll")                                                                \
            for (int fr = 0; fr < 4; ++fr)                                                   \
                a[fr] = *(const bf16x8*)((SRC) + EA_SW(fr * 16 + row16, k0 + kgrp * 8));     \
            _Pragma("unroll")                                                                \
            for (int fc = 0; fc < 4; ++fc)                                                   \
                b[fc] = *(const bf16x8*)(W1t + (wcol + fc * 16 + row16) * K1 + (KBASE) + k0 + kgrp * 8); \
            _Pragma("unroll")                                                                \
            for (int fr = 0; fr < 4; ++fr)                                                   \
                _Pragma("unroll")                                                            \
                for (int fc = 0; fc < 4; ++fc)                                               \
                    acc[fr][fc] = __builtin_amdgcn_mfma_f32_16x16x32_bf16(a[fr], b[fc], acc[fr][fc], 0, 0, 0); \
        }                                                                                    \
    }

    __syncthreads();

    // ---- sub-phase 0: prefetch xr; MFMA(xs); write xr -> s1 ----
    {
        bf16x8 xr[4];
        const ushort* src = Xb + (long)sr.y * D + sq * 32;
        #pragma unroll
        for (int j = 0; j < 4; ++j) xr[j] = *(const bf16x8*)(src + j * 8);
        PHASE1_MFMA(s0, 0)
        #pragma unroll
        for (int j = 0; j < 4; ++j)
            *(bf16x8*)(s1 + EA_SW(srow, sq * 32 + j * 8)) = xr[j];
    }
    __syncthreads();

    // ---- sub-phase 1: prefetch ea (f32->bf16); MFMA(xr); write ea -> s0 ----
    {
        bf16x8 er[4];
        const float* src = ea + se * D + sq * 32;
        #pragma unroll
        for (int j = 0; j < 4; ++j) {
            float4 v0 = ((const float4*)src)[2 * j];
            float4 v1 = ((const float4*)src)[2 * j + 1];
            union { bf16x8 v; ushort4 u[2]; } w;
            w.u[0] = cvt4(v0); w.u[1] = cvt4(v1);
            er[j] = w.v;
        }
        PHASE1_MFMA(s1, 128)
        #pragma unroll
        for (int j = 0; j < 4; ++j)
            *(bf16x8*)(s0 + EA_SW(srow, sq * 32 + j * 8)) = er[j];
    }
    __syncthreads();

    // ---- sub-phase 2: MFMA(ea) ----
    PHASE1_MFMA(s0, 256)
    __syncthreads();   // s0 reads done before aliasing as sH

    // ---- bias + relu + h -> LDS (bf16, swizzled) ----
    {
        float bv[4];
        #pragma unroll
        for (int fc = 0; fc < 4; ++fc) bv[fc] = b1[wcol + fc * 16 + row16];
        #pragma unroll
        for (int fr = 0; fr < 4; ++fr)
            #pragma unroll
            for (int r = 0; r < 4; ++r) {
                int row = fr * 16 + kgrp * 4 + r;
                #pragma unroll
                for (int fc = 0; fc < 4; ++fc) {
                    float v = fmaxf(acc[fr][fc][r] + bv[fc], 0.f);
                    sH[H_SW(row, wcol + fc * 16 + row16)] = f2b(v);
                }
            }
    }
    __syncthreads();

    // ---- phase 2: out = h @ W2 + b2 ----
    f32x4 acc2[4][2];
    #pragma unroll
    for (int a = 0; a < 4; ++a)
        #pragma unroll
        for (int b = 0; b < 2; ++b) acc2[a][b] = (f32x4){0, 0, 0, 0};

    const int wo = wave * 32;
    #pragma unroll
    for (int ks = 0; ks < 8; ++ks) {
        int k0 = ks * 32;
        bf16x8 a[4], b[2];
        #pragma unroll
        for (int fr = 0; fr < 4; ++fr)
            a[fr] = *(const bf16x8*)(sH + H_SW(fr * 16 + row16, k0 + kgrp * 8));
        #pragma unroll
        for (int fc = 0; fc < 2; ++fc)
            b[fc] = *(const bf16x8*)(W2t + (wo + fc * 16 + row16) * H + k0 + kgrp * 8);
        #pragma unroll
        for (int fr = 0; fr < 4; ++fr)
            #pragma unroll
            for (int fc = 0; fc < 2; ++fc)
                acc2[fr][fc] = __builtin_amdgcn_mfma_f32_16x16x32_bf16(a[fr], b[fc], acc2[fr][fc], 0, 0, 0);
    }
    __syncthreads();   // sH reads done before aliasing as sOut

    // ---- stage out tile (f32, swizzled) ----
    {
        float bv[2];
        #pragma unroll
        for (int fc = 0; fc < 2; ++fc) bv[fc] = b2[wo + fc * 16 + row16];
        #pragma unroll
        for (int fc = 0; fc < 2; ++fc)
            #pragma unroll
            for (int fr = 0; fr < 4; ++fr)
                #pragma unroll
                for (int r = 0; r < 4; ++r) {
                    int row = fr * 16 + kgrp * 4 + r;
                    sOut[O_SW(row, wo + fc * 16 + row16)] = acc2[fr][fc][r] + bv[fc];
                }
    }
    __syncthreads();

    // ---- coalesced store: each wave-instruction covers 1 KB contiguous ----
    #pragma unroll
    for (int c = 0; c < 8; ++c) {
        int idx = c * 256 + tid;           // 0..2047 float4 of the 64x128 tile
        int row = idx >> 5;
        int col4 = idx & 31;
        long eo = e0 + row;
        if (eo < E) {
            f32x4 v = *(const f32x4*)(sOut + O_SW(row, col4 * 4));
            *(f32x4*)(out + eo * O + col4 * 4) = v;
        }
    }
}

// ---------------- fallback kernel: used only if ws too small ----------------
__global__ __launch_bounds__(256, 2)
void edge_mlp(const float* __restrict__ x, const float* __restrict__ ea,
              const int* __restrict__ eidx,
              const float* __restrict__ b1, const float* __restrict__ b2,
              const ushort* __restrict__ W1t, const ushort* __restrict__ W2t,
              float* __restrict__ out, int E) {
    __shared__ ushort sF[64 * LDF];
    ushort* sH = sF;
    const int tid = threadIdx.x, wave = tid >> 6, lane = tid & 63;
    const int row16 = lane & 15, kgrp = lane >> 4;
    const long e0 = (long)blockIdx.x * 64;
    {
        int i = tid >> 2, p = tid & 3;
        long e = e0 + i; if (e >= E) e = E - 1;
        int s = eidx[2 * e], r = eidx[2 * e + 1];
        const float* src0 = x + (long)s * D + p * 32;
        const float* src1 = x + (long)r * D + p * 32;
        const float* src2 = ea + e * D + p * 32;
        ushort* dst = sF + i * LDF + p * 32;
        #pragma unroll
        for (int j = 0; j < 8; ++j) *(ushort4*)(dst + 0 * D + j * 4) = cvt4(((const float4*)src0)[j]);
        #pragma unroll
        for (int j = 0; j < 8; ++j) *(ushort4*)(dst + 1 * D + j * 4) = cvt4(((const float4*)src1)[j]);
        #pragma unroll
        for (int j = 0; j < 8; ++j) *(ushort4*)(dst + 2 * D + j * 4) = cvt4(((const float4*)src2)[j]);
    }
    __syncthreads();
    f32x4 acc[4][4];
    #pragma unroll
    for (int a = 0; a < 4; ++a)
        #pragma unroll
        for (int b = 0; b < 4; ++b) acc[a][b] = (f32x4){0,0,0,0};
    const int wcol = wave * 64;
    for (int k0 = 0; k0 < K1; k0 += 32) {
        bf16x8 a[4], b[4];
        #pragma unroll
        for (int fr = 0; fr < 4; ++fr)
            a[fr] = *(const bf16x8*)(sF + (fr * 16 + row16) * LDF + k0 + kgrp * 8);
        #pragma unroll
        for (int fc = 0; fc < 4; ++fc)
            b[fc] = *(const bf16x8*)(W1t + (wcol + fc * 16 + row16) * K1 + k0 + kgrp * 8);
        #pragma unroll
        for (int fr = 0; fr < 4; ++fr)
            #pragma unroll
            for (int fc = 0; fc < 4; ++fc)
                acc[fr][fc] = __builtin_amdgcn_mfma_f32_16x16x32_bf16(a[fr], b[fc], acc[fr][fc], 0, 0, 0);
    }
    __syncthreads();
    #pragma unroll
    for (int fc = 0; fc < 4; ++fc) {
        int col = wcol + fc * 16 + row16;
        float bv = b1[col];
        #pragma unroll
        for (int fr = 0; fr < 4; ++fr)
            #pragma unroll
            for (int r = 0; r < 4; ++r) {
                int row = fr * 16 + kgrp * 4 + r;
                sH[row * LDHF + col] = f2b(fmaxf(acc[fr][fc][r] + bv, 0.f));
            }
    }
    __syncthreads();
    f32x4 acc2[4][2];
    #pragma unroll
    for (int a = 0; a < 4; ++a)
        #pragma unroll
        for (int b = 0; b < 2; ++b) acc2[a][b] = (f32x4){0,0,0,0};
    const int wo = wave * 32;
    for (int k0 = 0; k0 < H; k0 += 32) {
        bf16x8 a[4], b[2];
        #pragma unroll
        for (int fr = 0; fr < 4; ++fr)
            a[fr] = *(const bf16x8*)(sH + (fr * 16 + row16) * LDHF + k0 + kgrp * 8);
        #pragma unroll
        for (int fc = 0; fc < 2; ++fc)
            b[fc] = *(const bf16x8*)(W2t + (wo + fc * 16 + row16) * H + k0 + kgrp * 8);
        #pragma unroll
        for (int fr = 0; fr < 4; ++fr)
            #pragma unroll
            for (int fc = 0; fc < 2; ++fc)
                acc2[fr][fc] = __builtin_amdgcn_mfma_f32_16x16x32_bf16(a[fr], b[fc], acc2[fr][fc], 0, 0, 0);
    }
    #pragma unroll
    for (int fc = 0; fc < 2; ++fc) {
        int col = wo + fc * 16 + row16;
        float bv = b2[col];
        #pragma unroll
        for (int fr = 0; fr < 4; ++fr)
            #pragma unroll
            for (int r = 0; r < 4; ++r) {
                long row = e0 + fr * 16 + kgrp * 4 + r;
                if (row < E) out[row * O + col] = acc2[fr][fc][r] + bv;
            }
    }
}

extern "C" void kernel_launch(void* const* d_in, const int* in_sizes, int n_in,
                              void* d_out, int out_size, void* d_ws, size_t ws_size,
                              hipStream_t stream) {
    const float* x  = (const float*)d_in[0];
    const float* ea = (const float*)d_in[1];
    const float* W1 = (const float*)d_in[2];
    const float* b1 = (const float*)d_in[3];
    const float* W2 = (const float*)d_in[4];
    const float* b2 = (const float*)d_in[5];
    const int* eidx = (const int*)d_in[6];
    float* out = (float*)d_out;

    const int E = in_sizes[1] / D;          // 500000
    const int N = in_sizes[0] / D;          // 50000

    ushort* W1t = (ushort*)d_ws;                    // 256*384
    ushort* W2t = W1t + 256 * 384;                  // 128*256
    ushort* Xb  = W2t + 128 * 256;                  // N*128 (12.8 MB)
    size_t need = ((size_t)(256 * 384 + 128 * 256) + (size_t)N * 128) * 2;

    prep_weights<<<512, 256, 0, stream>>>(W1, W2, W1t, W2t);

    if (ws_size >= need) {
        long total8 = (long)N * D / 8;
        int nbx = (int)((total8 + 255) / 256);
        prep_x<<<nbx, 256, 0, stream>>>(x, Xb, total8);
        int nb = (E + BE - 1) / BE;
        edge_mlp5<<<nb, 256, 0, stream>>>(ea, eidx, Xb, W1t, W2t, b1, b2, out, E);
    } else {
        int nb = (E + 63) / 64;
        edge_mlp<<<nb, 256, 0, stream>>>(x, ea, eidx, b1, b2, W1t, W2t, out, E);
    }
}

// Round 8
// 384.128 us; speedup vs baseline: 2.0783x; 1.0142x over previous
//
#include <hip/hip_runtime.h>
#include <hip/hip_bf16.h>

#define D 128
#define K1 384
#define H 256
#define O 128
#define BE 64
#define LDF (K1 + 8)   // fallback path feat leading dim
#define LDHF (H + 8)

typedef __attribute__((ext_vector_type(8))) short bf16x8;
typedef __attribute__((ext_vector_type(4))) float f32x4;

// XOR-swizzled LDS helpers (dense; 8-elem groups stay contiguous)
#define EA_SW(row, col) ((row) * 128 + ((col) ^ (((row) & 7) << 3)))   // ushort, col<128
#define H_SW(row, col)  ((row) * 256 + ((col) ^ (((row) & 7) << 3)))   // ushort, col<256

__device__ inline ushort f2b(float f) {
    union { float f; unsigned u; } v; v.f = f;
    unsigned u = v.u;
    unsigned r = (u + 0x7fffu + ((u >> 16) & 1u)) >> 16;   // RNE
    return (ushort)r;
}
__device__ inline ushort4 cvt4(float4 v) {
    ushort4 u; u.x = f2b(v.x); u.y = f2b(v.y); u.z = f2b(v.z); u.w = f2b(v.w); return u;
}

// W1t[n][k] = bf16(W1[k][n]) (n<256,k<384) ; W2t[o][k] = bf16(W2[k][o]) (o<128,k<256)
__global__ void prep_weights(const float* __restrict__ W1, const float* __restrict__ W2,
                             ushort* __restrict__ W1t, ushort* __restrict__ W2t) {
    int tid = blockIdx.x * blockDim.x + threadIdx.x;
    if (tid < 256 * 384) {
        int n = tid / 384, k = tid % 384;
        W1t[tid] = f2b(W1[k * 256 + n]);
    } else {
        int t2 = tid - 256 * 384;
        if (t2 < 128 * 256) {
            int o = t2 / 256, k = t2 % 256;
            W2t[t2] = f2b(W2[k * 128 + o]);
        }
    }
}

// Xb[n][d] = bf16(x[n][d]) — 12.8 MB table, L3-resident gather target
__global__ __launch_bounds__(256)
void prep_x(const float* __restrict__ x, ushort* __restrict__ Xb, long total8) {
    long t = (long)blockIdx.x * blockDim.x + threadIdx.x;
    if (t < total8) {
        const float* src = x + t * 8;
        float4 v0 = ((const float4*)src)[0], v1 = ((const float4*)src)[1];
        union { bf16x8 v; ushort4 u[2]; } w;
        w.u[0] = cvt4(v0); w.u[1] = cvt4(v1);
        *(bf16x8*)(Xb + t * 8) = w.v;
    }
}

// BE=64 tile, 48 KB LDS (xs|xr|ea staged up-front), 3 blocks/CU, 3 barriers.
// No register prefetch (spill-free under launch_bounds(256,3)); direct epilogue store.
__global__ __launch_bounds__(256, 3)
void edge_mlp6(const float* __restrict__ ea, const int* __restrict__ eidx,
               const ushort* __restrict__ Xb,
               const ushort* __restrict__ W1t, const ushort* __restrict__ W2t,
               const float* __restrict__ b1, const float* __restrict__ b2,
               float* __restrict__ out, int E) {
    __shared__ __align__(16) ushort sBuf[24576];   // 48 KB
    ushort* s0 = sBuf;                // xs  (16 KB)
    ushort* s1 = sBuf + 8192;         // xr  (16 KB)
    ushort* s2 = sBuf + 16384;        // ea  (16 KB)
    ushort* sH = sBuf;                // h   (32 KB, aliases s0+s1 after phase-1 reads)

    const int tid = threadIdx.x, wave = tid >> 6, lane = tid & 63;
    const int row16 = lane & 15, kgrp = lane >> 4;
    const long e0 = (long)blockIdx.x * BE;

    // ---- stage all of tile: xs, xr (bf16 gathers) and ea (f32->bf16), loads co-inflight ----
    {
        const int srow = tid >> 2, sq = tid & 3;
        long se = e0 + srow; if (se >= E) se = E - 1;
        const int2 sr = *(const int2*)(eidx + 2 * se);

        const ushort* srcS = Xb + (long)sr.x * D + sq * 32;
        const ushort* srcR = Xb + (long)sr.y * D + sq * 32;
        const float*  srcE = ea + se * D + sq * 32;

        #pragma unroll
        for (int j = 0; j < 4; ++j)
            *(bf16x8*)(s0 + EA_SW(srow, sq * 32 + j * 8)) = *(const bf16x8*)(srcS + j * 8);
        #pragma unroll
        for (int j = 0; j < 4; ++j)
            *(bf16x8*)(s1 + EA_SW(srow, sq * 32 + j * 8)) = *(const bf16x8*)(srcR + j * 8);
        #pragma unroll
        for (int j = 0; j < 4; ++j) {
            float4 v0 = ((const float4*)srcE)[2 * j];
            float4 v1 = ((const float4*)srcE)[2 * j + 1];
            union { bf16x8 v; ushort4 u[2]; } w;
            w.u[0] = cvt4(v0); w.u[1] = cvt4(v1);
            *(bf16x8*)(s2 + EA_SW(srow, sq * 32 + j * 8)) = w.v;
        }
    }

    f32x4 acc[4][4];
    #pragma unroll
    for (int a = 0; a < 4; ++a)
        #pragma unroll
        for (int b = 0; b < 4; ++b) acc[a][b] = (f32x4){0, 0, 0, 0};

    const int wcol = wave * 64;

#define PHASE1_MFMA(SRC, KBASE)                                                              \
    {                                                                                        \
        _Pragma("unroll")                                                                    \
        for (int ks = 0; ks < 4; ++ks) {                                                     \
            int k0 = ks * 32;                                                                \
            bf16x8 a[4], b[4];                                                               \
            _Pragma("unroll")                                                                \
            for (int fr = 0; fr < 4; ++fr)                                                   \
                a[fr] = *(const bf16x8*)((SRC) + EA_SW(fr * 16 + row16, k0 + kgrp * 8));     \
            _Pragma("unroll")                                                                \
            for (int fc = 0; fc < 4; ++fc)                                                   \
                b[fc] = *(const bf16x8*)(W1t + (wcol + fc * 16 + row16) * K1 + (KBASE) + k0 + kgrp * 8); \
            _Pragma("unroll")                                                                \
            for (int fr = 0; fr < 4; ++fr)                                                   \
                _Pragma("unroll")                                                            \
                for (int fc = 0; fc < 4; ++fc)                                               \
                    acc[fr][fc] = __builtin_amdgcn_mfma_f32_16x16x32_bf16(a[fr], b[fc], acc[fr][fc], 0, 0, 0); \
        }                                                                                    \
    }

    __syncthreads();

    // ---- phase 1a/1b: xs and xr sub-GEMMs (each wave fully consumes s0,s1) ----
    PHASE1_MFMA(s0, 0)
    PHASE1_MFMA(s1, 128)
    __syncthreads();   // all waves done reading s0/s1 before sH overwrites them

    // ---- phase 1c: ea sub-GEMM (s2 untouched by sH) ----
    PHASE1_MFMA(s2, 256)

    // ---- bias + relu + h -> sH (bf16, swizzled; aliases s0+s1) ----
    {
        float bv[4];
        #pragma unroll
        for (int fc = 0; fc < 4; ++fc) bv[fc] = b1[wcol + fc * 16 + row16];
        #pragma unroll
        for (int fr = 0; fr < 4; ++fr)
            #pragma unroll
            for (int r = 0; r < 4; ++r) {
                int row = fr * 16 + kgrp * 4 + r;
                #pragma unroll
                for (int fc = 0; fc < 4; ++fc) {
                    float v = fmaxf(acc[fr][fc][r] + bv[fc], 0.f);
                    sH[H_SW(row, wcol + fc * 16 + row16)] = f2b(v);
                }
            }
    }
    __syncthreads();

    // ---- phase 2: out = h @ W2 + b2 ----
    f32x4 acc2[4][2];
    #pragma unroll
    for (int a = 0; a < 4; ++a)
        #pragma unroll
        for (int b = 0; b < 2; ++b) acc2[a][b] = (f32x4){0, 0, 0, 0};

    const int wo = wave * 32;
    #pragma unroll
    for (int ks = 0; ks < 8; ++ks) {
        int k0 = ks * 32;
        bf16x8 a[4], b[2];
        #pragma unroll
        for (int fr = 0; fr < 4; ++fr)
            a[fr] = *(const bf16x8*)(sH + H_SW(fr * 16 + row16, k0 + kgrp * 8));
        #pragma unroll
        for (int fc = 0; fc < 2; ++fc)
            b[fc] = *(const bf16x8*)(W2t + (wo + fc * 16 + row16) * H + k0 + kgrp * 8);
        #pragma unroll
        for (int fr = 0; fr < 4; ++fr)
            #pragma unroll
            for (int fc = 0; fc < 2; ++fc)
                acc2[fr][fc] = __builtin_amdgcn_mfma_f32_16x16x32_bf16(a[fr], b[fc], acc2[fr][fc], 0, 0, 0);
    }

    // ---- direct epilogue store (R1 pattern — L2 merges; near-ideal WRITE when no spill) ----
    #pragma unroll
    for (int fc = 0; fc < 2; ++fc) {
        int col = wo + fc * 16 + row16;
        float bv = b2[col];
        #pragma unroll
        for (int fr = 0; fr < 4; ++fr)
            #pragma unroll
            for (int r = 0; r < 4; ++r) {
                long row = e0 + fr * 16 + kgrp * 4 + r;
                if (row < E) out[row * O + col] = acc2[fr][fc][r] + bv;
            }
    }
}

// ---------------- fallback kernel: used only if ws too small ----------------
__global__ __launch_bounds__(256, 2)
void edge_mlp(const float* __restrict__ x, const float* __restrict__ ea,
              const int* __restrict__ eidx,
              const float* __restrict__ b1, const float* __restrict__ b2,
              const ushort* __restrict__ W1t, const ushort* __restrict__ W2t,
              float* __restrict__ out, int E) {
    __shared__ ushort sF[64 * LDF];
    ushort* sH = sF;
    const int tid = threadIdx.x, wave = tid >> 6, lane = tid & 63;
    const int row16 = lane & 15, kgrp = lane >> 4;
    const long e0 = (long)blockIdx.x * 64;
    {
        int i = tid >> 2, p = tid & 3;
        long e = e0 + i; if (e >= E) e = E - 1;
        int s = eidx[2 * e], r = eidx[2 * e + 1];
        const float* src0 = x + (long)s * D + p * 32;
        const float* src1 = x + (long)r * D + p * 32;
        const float* src2 = ea + e * D + p * 32;
        ushort* dst = sF + i * LDF + p * 32;
        #pragma unroll
        for (int j = 0; j < 8; ++j) *(ushort4*)(dst + 0 * D + j * 4) = cvt4(((const float4*)src0)[j]);
        #pragma unroll
        for (int j = 0; j < 8; ++j) *(ushort4*)(dst + 1 * D + j * 4) = cvt4(((const float4*)src1)[j]);
        #pragma unroll
        for (int j = 0; j < 8; ++j) *(ushort4*)(dst + 2 * D + j * 4) = cvt4(((const float4*)src2)[j]);
    }
    __syncthreads();
    f32x4 acc[4][4];
    #pragma unroll
    for (int a = 0; a < 4; ++a)
        #pragma unroll
        for (int b = 0; b < 4; ++b) acc[a][b] = (f32x4){0,0,0,0};
    const int wcol = wave * 64;
    for (int k0 = 0; k0 < K1; k0 += 32) {
        bf16x8 a[4], b[4];
        #pragma unroll
        for (int fr = 0; fr < 4; ++fr)
            a[fr] = *(const bf16x8*)(sF + (fr * 16 + row16) * LDF + k0 + kgrp * 8);
        #pragma unroll
        for (int fc = 0; fc < 4; ++fc)
            b[fc] = *(const bf16x8*)(W1t + (wcol + fc * 16 + row16) * K1 + k0 + kgrp * 8);
        #pragma unroll
        for (int fr = 0; fr < 4; ++fr)
            #pragma unroll
            for (int fc = 0; fc < 4; ++fc)
                acc[fr][fc] = __builtin_amdgcn_mfma_f32_16x16x32_bf16(a[fr], b[fc], acc[fr][fc], 0, 0, 0);
    }
    __syncthreads();
    #pragma unroll
    for (int fc = 0; fc < 4; ++fc) {
        int col = wcol + fc * 16 + row16;
        float bv = b1[col];
        #pragma unroll
        for (int fr = 0; fr < 4; ++fr)
            #pragma unroll
            for (int r = 0; r < 4; ++r) {
                int row = fr * 16 + kgrp * 4 + r;
                sH[row * LDHF + col] = f2b(fmaxf(acc[fr][fc][r] + bv, 0.f));
            }
    }
    __syncthreads();
    f32x4 acc2[4][2];
    #pragma unroll
    for (int a = 0; a < 4; ++a)
        #pragma unroll
        for (int b = 0; b < 2; ++b) acc2[a][b] = (f32x4){0,0,0,0};
    const int wo = wave * 32;
    for (int k0 = 0; k0 < H; k0 += 32) {
        bf16x8 a[4], b[2];
        #pragma unroll
        for (int fr = 0; fr < 4; ++fr)
            a[fr] = *(const bf16x8*)(sH + (fr * 16 + row16) * LDHF + k0 + kgrp * 8);
        #pragma unroll
        for (int fc = 0; fc < 2; ++fc)
            b[fc] = *(const bf16x8*)(W2t + (wo + fc * 16 + row16) * H + k0 + kgrp * 8);
        #pragma unroll
        for (int fr = 0; fr < 4; ++fr)
            #pragma unroll
            for (int fc = 0; fc < 2; ++fc)
                acc2[fr][fc] = __builtin_amdgcn_mfma_f32_16x16x32_bf16(a[fr], b[fc], acc2[fr][fc], 0, 0, 0);
    }
    #pragma unroll
    for (int fc = 0; fc < 2; ++fc) {
        int col = wo + fc * 16 + row16;
        float bv = b2[col];
        #pragma unroll
        for (int fr = 0; fr < 4; ++fr)
            #pragma unroll
            for (int r = 0; r < 4; ++r) {
                long row = e0 + fr * 16 + kgrp * 4 + r;
                if (row < E) out[row * O + col] = acc2[fr][fc][r] + bv;
            }
    }
}

extern "C" void kernel_launch(void* const* d_in, const int* in_sizes, int n_in,
                              void* d_out, int out_size, void* d_ws, size_t ws_size,
                              hipStream_t stream) {
    const float* x  = (const float*)d_in[0];
    const float* ea = (const float*)d_in[1];
    const float* W1 = (const float*)d_in[2];
    const float* b1 = (const float*)d_in[3];
    const float* W2 = (const float*)d_in[4];
    const float* b2 = (const float*)d_in[5];
    const int* eidx = (const int*)d_in[6];
    float* out = (float*)d_out;

    const int E = in_sizes[1] / D;          // 500000
    const int N = in_sizes[0] / D;          // 50000

    ushort* W1t = (ushort*)d_ws;                    // 256*384
    ushort* W2t = W1t + 256 * 384;                  // 128*256
    ushort* Xb  = W2t + 128 * 256;                  // N*128 (12.8 MB)
    size_t need = ((size_t)(256 * 384 + 128 * 256) + (size_t)N * 128) * 2;

    prep_weights<<<512, 256, 0, stream>>>(W1, W2, W1t, W2t);

    if (ws_size >= need) {
        long total8 = (long)N * D / 8;
        int nbx = (int)((total8 + 255) / 256);
        prep_x<<<nbx, 256, 0, stream>>>(x, Xb, total8);
        int nb = (E + BE - 1) / BE;
        edge_mlp6<<<nb, 256, 0, stream>>>(ea, eidx, Xb, W1t, W2t, b1, b2, out, E);
    } else {
        int nb = (E + 63) / 64;
        edge_mlp<<<nb, 256, 0, stream>>>(x, ea, eidx, b1, b2, W1t, W2t, out, E);
    }
}

// Round 10
// 301.217 us; speedup vs baseline: 2.6504x; 1.2753x over previous
//
#include <hip/hip_runtime.h>
#include <hip/hip_bf16.h>

#define D 128
#define K1 384
#define H 256
#define O 128
#define BE 64
#define GRIDP 256
#define LDF (K1 + 8)   // fallback path feat leading dim
#define LDHF (H + 8)

typedef __attribute__((ext_vector_type(8))) short bf16x8;
typedef __attribute__((ext_vector_type(4))) float f32x4;

// XOR-swizzle (bits 3-5 of ushort col index; 8-elem groups stay contiguous)
#define SSW(row, col) ((row) * 128 + ((col) ^ (((row) & 7) << 3)))   // staging tiles, col<128
#define HSW(row, col) ((row) * 256 + ((col) ^ (((row) & 7) << 3)))   // h tile, col<256

__device__ inline ushort f2b(float f) {
    union { float f; unsigned u; } v; v.f = f;
    unsigned u = v.u;
    unsigned r = (u + 0x7fffu + ((u >> 16) & 1u)) >> 16;   // RNE
    return (ushort)r;
}
__device__ inline ushort4 cvt4(float4 v) {
    ushort4 u; u.x = f2b(v.x); u.y = f2b(v.y); u.z = f2b(v.z); u.w = f2b(v.w); return u;
}
__device__ inline bf16x8 cvt8(f32x4 a, f32x4 b) {
    union { bf16x8 v; ushort u[8]; } w;
    w.u[0] = f2b(a[0]); w.u[1] = f2b(a[1]); w.u[2] = f2b(a[2]); w.u[3] = f2b(a[3]);
    w.u[4] = f2b(b[0]); w.u[5] = f2b(b[1]); w.u[6] = f2b(b[2]); w.u[7] = f2b(b[3]);
    return w.v;
}

// W1t[n][k] = bf16(W1[k][n]) (n<256,k<384) ; W2t[o][k] = bf16(W2[k][o]) (o<128,k<256)
__global__ void prep_weights(const float* __restrict__ W1, const float* __restrict__ W2,
                             ushort* __restrict__ W1t, ushort* __restrict__ W2t) {
    int tid = blockIdx.x * blockDim.x + threadIdx.x;
    if (tid < 256 * 384) {
        int n = tid / 384, k = tid % 384;
        W1t[tid] = f2b(W1[k * 256 + n]);
    } else {
        int t2 = tid - 256 * 384;
        if (t2 < 128 * 256) {
            int o = t2 / 256, k = t2 % 256;
            W2t[t2] = f2b(W2[k * 128 + o]);
        }
    }
}

// Xb[n][d] = bf16(x[n][d]) — 12.8 MB gather table
__global__ __launch_bounds__(256)
void prep_x(const float* __restrict__ x, ushort* __restrict__ Xb, long total8) {
    long t = (long)blockIdx.x * blockDim.x + threadIdx.x;
    if (t < total8) {
        const float* src = x + t * 8;
        float4 v0 = ((const float4*)src)[0], v1 = ((const float4*)src)[1];
        union { bf16x8 v; ushort4 u[2]; } w;
        w.u[0] = cvt4(v0); w.u[1] = cvt4(v1);
        *(bf16x8*)(Xb + t * 8) = w.v;
    }
}

// Persistent pipelined kernel: 512 thr (8 waves), BE=64 per tile, weights in registers,
// grid = 256 (1 block/CU), cross-tile prefetch with the only vmcnt wait fully aged.
__global__ __launch_bounds__(512, 2)
void edge_mlp8(const float* __restrict__ ea, const int* __restrict__ eidx,
               const ushort* __restrict__ Xb,
               const ushort* __restrict__ W1t, const ushort* __restrict__ W2t,
               const float* __restrict__ b1, const float* __restrict__ b2,
               float* __restrict__ out, int E, int ntiles) {
    __shared__ __align__(16) ushort sBuf[24576];   // 48 KB: s0|s1|s2 ; sH aliases s0+s1
    ushort* s0 = sBuf;
    ushort* s1 = sBuf + 8192;
    ushort* s2 = sBuf + 16384;
    ushort* sH = sBuf;

    const int tid = threadIdx.x;
    const int wave = tid >> 6, lane = tid & 63;
    const int row16 = lane & 15, kgrp = lane >> 4;
    const int srow = tid >> 3, oct = tid & 7;     // staging: 8 threads per edge-row

    // ---- persistent per-wave weight fragments (the key: no in-loop global loads) ----
    bf16x8 w1f[12][2];      // phase1: cols [wave*32, +32), fc in {0,1}; ks*32 spans K=384
    #pragma unroll
    for (int ks = 0; ks < 12; ++ks)
        #pragma unroll
        for (int fc = 0; fc < 2; ++fc)
            w1f[ks][fc] = *(const bf16x8*)(W1t + (wave * 32 + fc * 16 + row16) * K1 + ks * 32 + kgrp * 8);
    bf16x8 w2f[8];          // phase2: out cols [wave*16, +16)
    #pragma unroll
    for (int ks = 0; ks < 8; ++ks)
        w2f[ks] = *(const bf16x8*)(W2t + (wave * 16 + row16) * H + ks * 32 + kgrp * 8);
    const float b1v0 = b1[wave * 32 + row16];
    const float b1v1 = b1[wave * 32 + 16 + row16];
    const float b2v  = b2[wave * 16 + row16];

    int t = blockIdx.x;
    if (t >= ntiles) return;

    bf16x8 pxs[2], pxr[2];
    f32x4  pea[4];

    // ---- prologue: stage tile t ----
    {
        long se = (long)t * BE + srow; if (se >= E) se = E - 1;
        int2 ei = *(const int2*)(eidx + 2 * se);
        const ushort* ps = Xb + (long)ei.x * D + oct * 16;
        const ushort* pr = Xb + (long)ei.y * D + oct * 16;
        const float*  pe = ea + se * D + oct * 16;
        #pragma unroll
        for (int j = 0; j < 2; ++j) pxs[j] = *(const bf16x8*)(ps + j * 8);
        #pragma unroll
        for (int j = 0; j < 2; ++j) pxr[j] = *(const bf16x8*)(pr + j * 8);
        #pragma unroll
        for (int j = 0; j < 4; ++j) pea[j] = ((const f32x4*)pe)[j];

        #pragma unroll
        for (int j = 0; j < 2; ++j) *(bf16x8*)(s0 + SSW(srow, oct * 16 + j * 8)) = pxs[j];
        #pragma unroll
        for (int j = 0; j < 2; ++j) *(bf16x8*)(s1 + SSW(srow, oct * 16 + j * 8)) = pxr[j];
        *(bf16x8*)(s2 + SSW(srow, oct * 16 + 0)) = cvt8(pea[0], pea[1]);
        *(bf16x8*)(s2 + SSW(srow, oct * 16 + 8)) = cvt8(pea[2], pea[3]);
    }

    int tn = t + GRIDP;
    int2 ei2;
    {
        int tc = (tn < ntiles) ? tn : (ntiles - 1);
        long se = (long)tc * BE + srow; if (se >= E) se = E - 1;
        ei2 = *(const int2*)(eidx + 2 * se);
    }

    while (true) {
        __syncthreads();                            // A: staging visible
        const bool hasNext = (tn < ntiles);
        if (hasNext) {
            // issue next tile's loads (in flight across phase1+phase2)
            long sen = (long)tn * BE + srow; if (sen >= E) sen = E - 1;
            const ushort* ps = Xb + (long)ei2.x * D + oct * 16;
            const ushort* pr = Xb + (long)ei2.y * D + oct * 16;
            const float*  pe = ea + sen * D + oct * 16;
            #pragma unroll
            for (int j = 0; j < 2; ++j) pxs[j] = *(const bf16x8*)(ps + j * 8);
            #pragma unroll
            for (int j = 0; j < 2; ++j) pxr[j] = *(const bf16x8*)(pr + j * 8);
            #pragma unroll
            for (int j = 0; j < 4; ++j) pea[j] = ((const f32x4*)pe)[j];
            // eidx two tiles ahead
            int tnn = tn + GRIDP;
            int tc = (tnn < ntiles) ? tnn : (ntiles - 1);
            long se2 = (long)tc * BE + srow; if (se2 >= E) se2 = E - 1;
            ei2 = *(const int2*)(eidx + 2 * se2);
        }

        // ---- phase 1: acc = feat(64x384) @ W1 (wave: 64 rows x 32 cols) ----
        f32x4 acc[4][2];
        #pragma unroll
        for (int fr = 0; fr < 4; ++fr) { acc[fr][0] = (f32x4){0,0,0,0}; acc[fr][1] = (f32x4){0,0,0,0}; }

        #pragma unroll
        for (int ks = 0; ks < 12; ++ks) {
            const ushort* sA = (ks < 4) ? s0 : ((ks < 8) ? s1 : s2);
            const int kl = (ks & 3) * 32 + kgrp * 8;
            bf16x8 a[4];
            #pragma unroll
            for (int fr = 0; fr < 4; ++fr)
                a[fr] = *(const bf16x8*)(sA + SSW(fr * 16 + row16, kl));
            #pragma unroll
            for (int fr = 0; fr < 4; ++fr) {
                acc[fr][0] = __builtin_amdgcn_mfma_f32_16x16x32_bf16(a[fr], w1f[ks][0], acc[fr][0], 0, 0, 0);
                acc[fr][1] = __builtin_amdgcn_mfma_f32_16x16x32_bf16(a[fr], w1f[ks][1], acc[fr][1], 0, 0, 0);
            }
        }
        __syncthreads();                            // B: staging reads done

        // ---- bias + relu -> sH (aliases s0+s1) ----
        #pragma unroll
        for (int fr = 0; fr < 4; ++fr)
            #pragma unroll
            for (int r = 0; r < 4; ++r) {
                int row = fr * 16 + kgrp * 4 + r;
                int swz = (row & 7) << 3;
                sH[row * 256 + ((wave * 32 + row16) ^ swz)]      = f2b(fmaxf(acc[fr][0][r] + b1v0, 0.f));
                sH[row * 256 + ((wave * 32 + 16 + row16) ^ swz)] = f2b(fmaxf(acc[fr][1][r] + b1v1, 0.f));
            }
        __syncthreads();                            // C: sH visible

        // ---- phase 2: out = h(64x256) @ W2 (wave: 64 rows x 16 cols) + store ----
        f32x4 acc2[4];
        #pragma unroll
        for (int fr = 0; fr < 4; ++fr) acc2[fr] = (f32x4){0,0,0,0};
        #pragma unroll
        for (int ks = 0; ks < 8; ++ks) {
            bf16x8 a[4];
            #pragma unroll
            for (int fr = 0; fr < 4; ++fr)
                a[fr] = *(const bf16x8*)(sH + HSW(fr * 16 + row16, ks * 32 + kgrp * 8));
            #pragma unroll
            for (int fr = 0; fr < 4; ++fr)
                acc2[fr] = __builtin_amdgcn_mfma_f32_16x16x32_bf16(a[fr], w2f[ks], acc2[fr], 0, 0, 0);
        }
        {
            const long e0 = (long)t * BE;
            #pragma unroll
            for (int fr = 0; fr < 4; ++fr)
                #pragma unroll
                for (int r = 0; r < 4; ++r) {
                    long erow = e0 + fr * 16 + kgrp * 4 + r;
                    if (erow < E) out[erow * O + wave * 16 + row16] = acc2[fr][r] + b2v;
                }
        }

        if (!hasNext) break;
        __syncthreads();                            // D: sH reads done, staging free
        // write next tile's staging (the only global-load wait; fully aged)
        #pragma unroll
        for (int j = 0; j < 2; ++j) *(bf16x8*)(s0 + SSW(srow, oct * 16 + j * 8)) = pxs[j];
        #pragma unroll
        for (int j = 0; j < 2; ++j) *(bf16x8*)(s1 + SSW(srow, oct * 16 + j * 8)) = pxr[j];
        *(bf16x8*)(s2 + SSW(srow, oct * 16 + 0)) = cvt8(pea[0], pea[1]);
        *(bf16x8*)(s2 + SSW(srow, oct * 16 + 8)) = cvt8(pea[2], pea[3]);

        t = tn; tn += GRIDP;
    }
}

// ---------------- fallback kernel: used only if ws too small ----------------
__global__ __launch_bounds__(256, 2)
void edge_mlp(const float* __restrict__ x, const float* __restrict__ ea,
              const int* __restrict__ eidx,
              const float* __restrict__ b1, const float* __restrict__ b2,
              const ushort* __restrict__ W1t, const ushort* __restrict__ W2t,
              float* __restrict__ out, int E) {
    __shared__ ushort sF[64 * LDF];
    ushort* sH = sF;
    const int tid = threadIdx.x, wave = tid >> 6, lane = tid & 63;
    const int row16 = lane & 15, kgrp = lane >> 4;
    const long e0 = (long)blockIdx.x * 64;
    {
        int i = tid >> 2, p = tid & 3;
        long e = e0 + i; if (e >= E) e = E - 1;
        int s = eidx[2 * e], r = eidx[2 * e + 1];
        const float* src0 = x + (long)s * D + p * 32;
        const float* src1 = x + (long)r * D + p * 32;
        const float* src2 = ea + e * D + p * 32;
        ushort* dst = sF + i * LDF + p * 32;
        #pragma unroll
        for (int j = 0; j < 8; ++j) *(ushort4*)(dst + 0 * D + j * 4) = cvt4(((const float4*)src0)[j]);
        #pragma unroll
        for (int j = 0; j < 8; ++j) *(ushort4*)(dst + 1 * D + j * 4) = cvt4(((const float4*)src1)[j]);
        #pragma unroll
        for (int j = 0; j < 8; ++j) *(ushort4*)(dst + 2 * D + j * 4) = cvt4(((const float4*)src2)[j]);
    }
    __syncthreads();
    f32x4 acc[4][4];
    #pragma unroll
    for (int a = 0; a < 4; ++a)
        #pragma unroll
        for (int b = 0; b < 4; ++b) acc[a][b] = (f32x4){0,0,0,0};
    const int wcol = wave * 64;
    for (int k0 = 0; k0 < K1; k0 += 32) {
        bf16x8 a[4], b[4];
        #pragma unroll
        for (int fr = 0; fr < 4; ++fr)
            a[fr] = *(const bf16x8*)(sF + (fr * 16 + row16) * LDF + k0 + kgrp * 8);
        #pragma unroll
        for (int fc = 0; fc < 4; ++fc)
            b[fc] = *(const bf16x8*)(W1t + (wcol + fc * 16 + row16) * K1 + k0 + kgrp * 8);
        #pragma unroll
        for (int fr = 0; fr < 4; ++fr)
            #pragma unroll
            for (int fc = 0; fc < 4; ++fc)
                acc[fr][fc] = __builtin_amdgcn_mfma_f32_16x16x32_bf16(a[fr], b[fc], acc[fr][fc], 0, 0, 0);
    }
    __syncthreads();
    #pragma unroll
    for (int fc = 0; fc < 4; ++fc) {
        int col = wcol + fc * 16 + row16;
        float bv = b1[col];
        #pragma unroll
        for (int fr = 0; fr < 4; ++fr)
            #pragma unroll
            for (int r = 0; r < 4; ++r) {
                int row = fr * 16 + kgrp * 4 + r;
                sH[row * LDHF + col] = f2b(fmaxf(acc[fr][fc][r] + bv, 0.f));
            }
    }
    __syncthreads();
    f32x4 acc2[4][2];
    #pragma unroll
    for (int a = 0; a < 4; ++a)
        #pragma unroll
        for (int b = 0; b < 2; ++b) acc2[a][b] = (f32x4){0,0,0,0};
    const int wo = wave * 32;
    for (int k0 = 0; k0 < H; k0 += 32) {
        bf16x8 a[4], b[2];
        #pragma unroll
        for (int fr = 0; fr < 4; ++fr)
            a[fr] = *(const bf16x8*)(sH + (fr * 16 + row16) * LDHF + k0 + kgrp * 8);
        #pragma unroll
        for (int fc = 0; fc < 2; ++fc)
            b[fc] = *(const bf16x8*)(W2t + (wo + fc * 16 + row16) * H + k0 + kgrp * 8);
        #pragma unroll
        for (int fr = 0; fr < 4; ++fr)
            #pragma unroll
            for (int fc = 0; fc < 2; ++fc)
                acc2[fr][fc] = __builtin_amdgcn_mfma_f32_16x16x32_bf16(a[fr], b[fc], acc2[fr][fc], 0, 0, 0);
    }
    #pragma unroll
    for (int fc = 0; fc < 2; ++fc) {
        int col = wo + fc * 16 + row16;
        float bv = b2[col];
        #pragma unroll
        for (int fr = 0; fr < 4; ++fr)
            #pragma unroll
            for (int r = 0; r < 4; ++r) {
                long row = e0 + fr * 16 + kgrp * 4 + r;
                if (row < E) out[row * O + col] = acc2[fr][fc][r] + bv;
            }
    }
}

extern "C" void kernel_launch(void* const* d_in, const int* in_sizes, int n_in,
                              void* d_out, int out_size, void* d_ws, size_t ws_size,
                              hipStream_t stream) {
    const float* x  = (const float*)d_in[0];
    const float* ea = (const float*)d_in[1];
    const float* W1 = (const float*)d_in[2];
    const float* b1 = (const float*)d_in[3];
    const float* W2 = (const float*)d_in[4];
    const float* b2 = (const float*)d_in[5];
    const int* eidx = (const int*)d_in[6];
    float* out = (float*)d_out;

    const int E = in_sizes[1] / D;          // 500000
    const int N = in_sizes[0] / D;          // 50000

    ushort* W1t = (ushort*)d_ws;                    // 256*384
    ushort* W2t = W1t + 256 * 384;                  // 128*256
    ushort* Xb  = W2t + 128 * 256;                  // N*128 (12.8 MB)
    size_t need = ((size_t)(256 * 384 + 128 * 256) + (size_t)N * 128) * 2;

    prep_weights<<<512, 256, 0, stream>>>(W1, W2, W1t, W2t);

    if (ws_size >= need) {
        long total8 = (long)N * D / 8;
        int nbx = (int)((total8 + 255) / 256);
        prep_x<<<nbx, 256, 0, stream>>>(x, Xb, total8);
        int ntiles = (E + BE - 1) / BE;
        int grid = (ntiles < GRIDP) ? ntiles : GRIDP;
        edge_mlp8<<<grid, 512, 0, stream>>>(ea, eidx, Xb, W1t, W2t, b1, b2, out, E, ntiles);
    } else {
        int nb = (E + 63) / 64;
        edge_mlp<<<nb, 256, 0, stream>>>(x, ea, eidx, b1, b2, W1t, W2t, out, E);
    }
}

// Round 11
// 216.446 us; speedup vs baseline: 3.6884x; 1.3916x over previous
//
#include <hip/hip_runtime.h>
#include <hip/hip_bf16.h>

#define D 128
#define K1 384
#define H 256
#define O 128
#define BE 64
#define GRIDP 256
#define LDF (K1 + 8)   // fallback path feat leading dim
#define LDHF (H + 8)

typedef __attribute__((ext_vector_type(8))) short bf16x8;
typedef __attribute__((ext_vector_type(4))) float f32x4;

// XOR-swizzle (bits 3-5 of ushort col index; 8-elem groups stay contiguous)
#define SSW(row, col) ((row) * 128 + ((col) ^ (((row) & 7) << 3)))   // staging tiles, col<128
#define HSW(row, col) ((row) * 256 + ((col) ^ (((row) & 7) << 3)))   // h tile, col<256

// Barrier that waits ONLY lgkmcnt (LDS ordering) — does NOT drain vmcnt, so
// prefetch global loads and out-stores stay in flight across it (T3/T4).
// Single asm block so nothing schedules between wait and barrier; "memory"
// clobber orders LDS ops; sched_barrier(0) guards against MFMA hoisting (rule 18).
#define LGKM_BARRIER()                                                 \
    do {                                                               \
        asm volatile("s_waitcnt lgkmcnt(0)\n\ts_barrier" ::: "memory");\
        __builtin_amdgcn_sched_barrier(0);                             \
    } while (0)

__device__ inline ushort f2b(float f) {
    union { float f; unsigned u; } v; v.f = f;
    unsigned u = v.u;
    unsigned r = (u + 0x7fffu + ((u >> 16) & 1u)) >> 16;   // RNE
    return (ushort)r;
}
__device__ inline ushort4 cvt4(float4 v) {
    ushort4 u; u.x = f2b(v.x); u.y = f2b(v.y); u.z = f2b(v.z); u.w = f2b(v.w); return u;
}
__device__ inline bf16x8 cvt8(f32x4 a, f32x4 b) {
    union { bf16x8 v; ushort u[8]; } w;
    w.u[0] = f2b(a[0]); w.u[1] = f2b(a[1]); w.u[2] = f2b(a[2]); w.u[3] = f2b(a[3]);
    w.u[4] = f2b(b[0]); w.u[5] = f2b(b[1]); w.u[6] = f2b(b[2]); w.u[7] = f2b(b[3]);
    return w.v;
}

// W1t[n][k] = bf16(W1[k][n]) (n<256,k<384) ; W2t[o][k] = bf16(W2[k][o]) (o<128,k<256)
__global__ void prep_weights(const float* __restrict__ W1, const float* __restrict__ W2,
                             ushort* __restrict__ W1t, ushort* __restrict__ W2t) {
    int tid = blockIdx.x * blockDim.x + threadIdx.x;
    if (tid < 256 * 384) {
        int n = tid / 384, k = tid % 384;
        W1t[tid] = f2b(W1[k * 256 + n]);
    } else {
        int t2 = tid - 256 * 384;
        if (t2 < 128 * 256) {
            int o = t2 / 256, k = t2 % 256;
            W2t[t2] = f2b(W2[k * 128 + o]);
        }
    }
}

// Xb[n][d] = bf16(x[n][d]) — 12.8 MB gather table
__global__ __launch_bounds__(256)
void prep_x(const float* __restrict__ x, ushort* __restrict__ Xb, long total8) {
    long t = (long)blockIdx.x * blockDim.x + threadIdx.x;
    if (t < total8) {
        const float* src = x + t * 8;
        float4 v0 = ((const float4*)src)[0], v1 = ((const float4*)src)[1];
        union { bf16x8 v; ushort4 u[2]; } w;
        w.u[0] = cvt4(v0); w.u[1] = cvt4(v1);
        *(bf16x8*)(Xb + t * 8) = w.v;
    }
}

// Persistent pipelined kernel: 512 thr (8 waves), BE=64/tile, weights in registers,
// grid=256 (1 block/CU). lgkm-only barriers keep prefetch loads in flight across
// the whole tile (no vmcnt(0) drains).
__global__ __launch_bounds__(512, 2)
void edge_mlp9(const float* __restrict__ ea, const int* __restrict__ eidx,
               const ushort* __restrict__ Xb,
               const ushort* __restrict__ W1t, const ushort* __restrict__ W2t,
               const float* __restrict__ b1, const float* __restrict__ b2,
               float* __restrict__ out, int E, int ntiles) {
    __shared__ __align__(16) ushort sBuf[24576];   // 48 KB: s0|s1|s2 ; sH aliases s0+s1
    ushort* s0 = sBuf;
    ushort* s1 = sBuf + 8192;
    ushort* s2 = sBuf + 16384;
    ushort* sH = sBuf;

    const int tid = threadIdx.x;
    const int wave = tid >> 6, lane = tid & 63;
    const int row16 = lane & 15, kgrp = lane >> 4;
    const int srow = tid >> 3, oct = tid & 7;     // staging: 8 threads per edge-row

    // ---- persistent per-wave weight fragments (no in-loop global loads) ----
    bf16x8 w1f[12][2];      // phase1: cols [wave*32, +32), fc in {0,1}; ks spans K=384
    #pragma unroll
    for (int ks = 0; ks < 12; ++ks)
        #pragma unroll
        for (int fc = 0; fc < 2; ++fc)
            w1f[ks][fc] = *(const bf16x8*)(W1t + (wave * 32 + fc * 16 + row16) * K1 + ks * 32 + kgrp * 8);
    bf16x8 w2f[8];          // phase2: out cols [wave*16, +16)
    #pragma unroll
    for (int ks = 0; ks < 8; ++ks)
        w2f[ks] = *(const bf16x8*)(W2t + (wave * 16 + row16) * H + ks * 32 + kgrp * 8);
    const float b1v0 = b1[wave * 32 + row16];
    const float b1v1 = b1[wave * 32 + 16 + row16];
    const float b2v  = b2[wave * 16 + row16];

    int t = blockIdx.x;
    if (t >= ntiles) return;

    bf16x8 pxs[2], pxr[2];
    f32x4  pea[4];

    // ---- prologue: stage tile t ----
    {
        long se = (long)t * BE + srow; if (se >= E) se = E - 1;
        int2 ei = *(const int2*)(eidx + 2 * se);
        const ushort* ps = Xb + (long)ei.x * D + oct * 16;
        const ushort* pr = Xb + (long)ei.y * D + oct * 16;
        const float*  pe = ea + se * D + oct * 16;
        #pragma unroll
        for (int j = 0; j < 2; ++j) pxs[j] = *(const bf16x8*)(ps + j * 8);
        #pragma unroll
        for (int j = 0; j < 2; ++j) pxr[j] = *(const bf16x8*)(pr + j * 8);
        #pragma unroll
        for (int j = 0; j < 4; ++j) pea[j] = ((const f32x4*)pe)[j];

        #pragma unroll
        for (int j = 0; j < 2; ++j) *(bf16x8*)(s0 + SSW(srow, oct * 16 + j * 8)) = pxs[j];
        #pragma unroll
        for (int j = 0; j < 2; ++j) *(bf16x8*)(s1 + SSW(srow, oct * 16 + j * 8)) = pxr[j];
        *(bf16x8*)(s2 + SSW(srow, oct * 16 + 0)) = cvt8(pea[0], pea[1]);
        *(bf16x8*)(s2 + SSW(srow, oct * 16 + 8)) = cvt8(pea[2], pea[3]);
    }

    int tn = t + GRIDP;
    int2 ei2;
    {
        int tc = (tn < ntiles) ? tn : (ntiles - 1);
        long se = (long)tc * BE + srow; if (se >= E) se = E - 1;
        ei2 = *(const int2*)(eidx + 2 * se);
    }

    while (true) {
        LGKM_BARRIER();                             // A: staging visible (LDS only)
        const bool hasNext = (tn < ntiles);
        if (hasNext) {
            // issue next tile's loads (stay in flight across phase1+phase2)
            long sen = (long)tn * BE + srow; if (sen >= E) sen = E - 1;
            const ushort* ps = Xb + (long)ei2.x * D + oct * 16;
            const ushort* pr = Xb + (long)ei2.y * D + oct * 16;
            const float*  pe = ea + sen * D + oct * 16;
            #pragma unroll
            for (int j = 0; j < 2; ++j) pxs[j] = *(const bf16x8*)(ps + j * 8);
            #pragma unroll
            for (int j = 0; j < 2; ++j) pxr[j] = *(const bf16x8*)(pr + j * 8);
            #pragma unroll
            for (int j = 0; j < 4; ++j) pea[j] = ((const f32x4*)pe)[j];
            // eidx two tiles ahead
            int tnn = tn + GRIDP;
            int tc = (tnn < ntiles) ? tnn : (ntiles - 1);
            long se2 = (long)tc * BE + srow; if (se2 >= E) se2 = E - 1;
            ei2 = *(const int2*)(eidx + 2 * se2);
        }

        // ---- phase 1: acc = feat(64x384) @ W1 (wave: 64 rows x 32 cols) ----
        f32x4 acc[4][2];
        #pragma unroll
        for (int fr = 0; fr < 4; ++fr) { acc[fr][0] = (f32x4){0,0,0,0}; acc[fr][1] = (f32x4){0,0,0,0}; }

        #pragma unroll
        for (int ks = 0; ks < 12; ++ks) {
            const ushort* sA = (ks < 4) ? s0 : ((ks < 8) ? s1 : s2);
            const int kl = (ks & 3) * 32 + kgrp * 8;
            bf16x8 a[4];
            #pragma unroll
            for (int fr = 0; fr < 4; ++fr)
                a[fr] = *(const bf16x8*)(sA + SSW(fr * 16 + row16, kl));
            #pragma unroll
            for (int fr = 0; fr < 4; ++fr) {
                acc[fr][0] = __builtin_amdgcn_mfma_f32_16x16x32_bf16(a[fr], w1f[ks][0], acc[fr][0], 0, 0, 0);
                acc[fr][1] = __builtin_amdgcn_mfma_f32_16x16x32_bf16(a[fr], w1f[ks][1], acc[fr][1], 0, 0, 0);
            }
        }
        LGKM_BARRIER();                             // B: staging reads done (LDS only)

        // ---- bias + relu -> sH (aliases s0+s1) ----
        #pragma unroll
        for (int fr = 0; fr < 4; ++fr)
            #pragma unroll
            for (int r = 0; r < 4; ++r) {
                int row = fr * 16 + kgrp * 4 + r;
                int swz = (row & 7) << 3;
                sH[row * 256 + ((wave * 32 + row16) ^ swz)]      = f2b(fmaxf(acc[fr][0][r] + b1v0, 0.f));
                sH[row * 256 + ((wave * 32 + 16 + row16) ^ swz)] = f2b(fmaxf(acc[fr][1][r] + b1v1, 0.f));
            }
        LGKM_BARRIER();                             // C: sH visible

        // ---- phase 2: out = h(64x256) @ W2 (wave: 64 rows x 16 cols) + store ----
        f32x4 acc2[4];
        #pragma unroll
        for (int fr = 0; fr < 4; ++fr) acc2[fr] = (f32x4){0,0,0,0};
        #pragma unroll
        for (int ks = 0; ks < 8; ++ks) {
            bf16x8 a[4];
            #pragma unroll
            for (int fr = 0; fr < 4; ++fr)
                a[fr] = *(const bf16x8*)(sH + HSW(fr * 16 + row16, ks * 32 + kgrp * 8));
            #pragma unroll
            for (int fr = 0; fr < 4; ++fr)
                acc2[fr] = __builtin_amdgcn_mfma_f32_16x16x32_bf16(a[fr], w2f[ks], acc2[fr], 0, 0, 0);
        }
        {
            const long e0 = (long)t * BE;
            #pragma unroll
            for (int fr = 0; fr < 4; ++fr)
                #pragma unroll
                for (int r = 0; r < 4; ++r) {
                    long erow = e0 + fr * 16 + kgrp * 4 + r;
                    if (erow < E) out[erow * O + wave * 16 + row16] = acc2[fr][r] + b2v;
                }
        }

        if (!hasNext) break;
        LGKM_BARRIER();                             // D: sH reads done, staging free
        // write next tile's staging; compiler waits counted vmcnt for pxs/pxr/pea
        // (loads are oldest in-order — wait does not drain the newer out-stores)
        #pragma unroll
        for (int j = 0; j < 2; ++j) *(bf16x8*)(s0 + SSW(srow, oct * 16 + j * 8)) = pxs[j];
        #pragma unroll
        for (int j = 0; j < 2; ++j) *(bf16x8*)(s1 + SSW(srow, oct * 16 + j * 8)) = pxr[j];
        *(bf16x8*)(s2 + SSW(srow, oct * 16 + 0)) = cvt8(pea[0], pea[1]);
        *(bf16x8*)(s2 + SSW(srow, oct * 16 + 8)) = cvt8(pea[2], pea[3]);

        t = tn; tn += GRIDP;
    }
}

// ---------------- fallback kernel: used only if ws too small ----------------
__global__ __launch_bounds__(256, 2)
void edge_mlp(const float* __restrict__ x, const float* __restrict__ ea,
              const int* __restrict__ eidx,
              const float* __restrict__ b1, const float* __restrict__ b2,
              const ushort* __restrict__ W1t, const ushort* __restrict__ W2t,
              float* __restrict__ out, int E) {
    __shared__ ushort sF[64 * LDF];
    ushort* sH = sF;
    const int tid = threadIdx.x, wave = tid >> 6, lane = tid & 63;
    const int row16 = lane & 15, kgrp = lane >> 4;
    const long e0 = (long)blockIdx.x * 64;
    {
        int i = tid >> 2, p = tid & 3;
        long e = e0 + i; if (e >= E) e = E - 1;
        int s = eidx[2 * e], r = eidx[2 * e + 1];
        const float* src0 = x + (long)s * D + p * 32;
        const float* src1 = x + (long)r * D + p * 32;
        const float* src2 = ea + e * D + p * 32;
        ushort* dst = sF + i * LDF + p * 32;
        #pragma unroll
        for (int j = 0; j < 8; ++j) *(ushort4*)(dst + 0 * D + j * 4) = cvt4(((const float4*)src0)[j]);
        #pragma unroll
        for (int j = 0; j < 8; ++j) *(ushort4*)(dst + 1 * D + j * 4) = cvt4(((const float4*)src1)[j]);
        #pragma unroll
        for (int j = 0; j < 8; ++j) *(ushort4*)(dst + 2 * D + j * 4) = cvt4(((const float4*)src2)[j]);
    }
    __syncthreads();
    f32x4 acc[4][4];
    #pragma unroll
    for (int a = 0; a < 4; ++a)
        #pragma unroll
        for (int b = 0; b < 4; ++b) acc[a][b] = (f32x4){0,0,0,0};
    const int wcol = wave * 64;
    for (int k0 = 0; k0 < K1; k0 += 32) {
        bf16x8 a[4], b[4];
        #pragma unroll
        for (int fr = 0; fr < 4; ++fr)
            a[fr] = *(const bf16x8*)(sF + (fr * 16 + row16) * LDF + k0 + kgrp * 8);
        #pragma unroll
        for (int fc = 0; fc < 4; ++fc)
            b[fc] = *(const bf16x8*)(W1t + (wcol + fc * 16 + row16) * K1 + k0 + kgrp * 8);
        #pragma unroll
        for (int fr = 0; fr < 4; ++fr)
            #pragma unroll
            for (int fc = 0; fc < 4; ++fc)
                acc[fr][fc] = __builtin_amdgcn_mfma_f32_16x16x32_bf16(a[fr], b[fc], acc[fr][fc], 0, 0, 0);
    }
    __syncthreads();
    #pragma unroll
    for (int fc = 0; fc < 4; ++fc) {
        int col = wcol + fc * 16 + row16;
        float bv = b1[col];
        #pragma unroll
        for (int fr = 0; fr < 4; ++fr)
            #pragma unroll
            for (int r = 0; r < 4; ++r) {
                int row = fr * 16 + kgrp * 4 + r;
                sH[row * LDHF + col] = f2b(fmaxf(acc[fr][fc][r] + bv, 0.f));
            }
    }
    __syncthreads();
    f32x4 acc2[4][2];
    #pragma unroll
    for (int a = 0; a < 4; ++a)
        #pragma unroll
        for (int b = 0; b < 2; ++b) acc2[a][b] = (f32x4){0,0,0,0};
    const int wo = wave * 32;
    for (int k0 = 0; k0 < H; k0 += 32) {
        bf16x8 a[4], b[2];
        #pragma unroll
        for (int fr = 0; fr < 4; ++fr)
            a[fr] = *(const bf16x8*)(sH + (fr * 16 + row16) * LDHF + k0 + kgrp * 8);
        #pragma unroll
        for (int fc = 0; fc < 2; ++fc)
            b[fc] = *(const bf16x8*)(W2t + (wo + fc * 16 + row16) * H + k0 + kgrp * 8);
        #pragma unroll
        for (int fr = 0; fr < 4; ++fr)
            #pragma unroll
            for (int fc = 0; fc < 2; ++fc)
                acc2[fr][fc] = __builtin_amdgcn_mfma_f32_16x16x32_bf16(a[fr], b[fc], acc2[fr][fc], 0, 0, 0);
    }
    #pragma unroll
    for (int fc = 0; fc < 2; ++fc) {
        int col = wo + fc * 16 + row16;
        float bv = b2[col];
        #pragma unroll
        for (int fr = 0; fr < 4; ++fr)
            #pragma unroll
            for (int r = 0; r < 4; ++r) {
                long row = e0 + fr * 16 + kgrp * 4 + r;
                if (row < E) out[row * O + col] = acc2[fr][fc][r] + bv;
            }
    }
}

extern "C" void kernel_launch(void* const* d_in, const int* in_sizes, int n_in,
                              void* d_out, int out_size, void* d_ws, size_t ws_size,
                              hipStream_t stream) {
    const float* x  = (const float*)d_in[0];
    const float* ea = (const float*)d_in[1];
    const float* W1 = (const float*)d_in[2];
    const float* b1 = (const float*)d_in[3];
    const float* W2 = (const float*)d_in[4];
    const float* b2 = (const float*)d_in[5];
    const int* eidx = (const int*)d_in[6];
    float* out = (float*)d_out;

    const int E = in_sizes[1] / D;          // 500000
    const int N = in_sizes[0] / D;          // 50000

    ushort* W1t = (ushort*)d_ws;                    // 256*384
    ushort* W2t = W1t + 256 * 384;                  // 128*256
    ushort* Xb  = W2t + 128 * 256;                  // N*128 (12.8 MB)
    size_t need = ((size_t)(256 * 384 + 128 * 256) + (size_t)N * 128) * 2;

    prep_weights<<<512, 256, 0, stream>>>(W1, W2, W1t, W2t);

    if (ws_size >= need) {
        long total8 = (long)N * D / 8;
        int nbx = (int)((total8 + 255) / 256);
        prep_x<<<nbx, 256, 0, stream>>>(x, Xb, total8);
        int ntiles = (E + BE - 1) / BE;
        int grid = (ntiles < GRIDP) ? ntiles : GRIDP;
        edge_mlp9<<<grid, 512, 0, stream>>>(ea, eidx, Xb, W1t, W2t, b1, b2, out, E, ntiles);
    } else {
        int nb = (E + 63) / 64;
        edge_mlp<<<nb, 256, 0, stream>>>(x, ea, eidx, b1, b2, W1t, W2t, out, E);
    }
}